// Round 3
// baseline (348.887 us; speedup 1.0000x reference)
//
#include <hip/hip_runtime.h>
#include <stdint.h>

#define BB 8
#define NN 2048
#define DD 128

typedef unsigned long long ull;

// insertion into sorted-ascending 8-slot register array (static indices only)
#define INS8(t8, cand) do { \
    t8[7] = (cand); ull _t; \
    if (t8[7] < t8[6]) { _t = t8[6]; t8[6] = t8[7]; t8[7] = _t; } \
    if (t8[6] < t8[5]) { _t = t8[5]; t8[5] = t8[6]; t8[6] = _t; } \
    if (t8[5] < t8[4]) { _t = t8[4]; t8[4] = t8[5]; t8[5] = _t; } \
    if (t8[4] < t8[3]) { _t = t8[3]; t8[3] = t8[4]; t8[4] = _t; } \
    if (t8[3] < t8[2]) { _t = t8[2]; t8[2] = t8[3]; t8[3] = _t; } \
    if (t8[2] < t8[1]) { _t = t8[1]; t8[1] = t8[2]; t8[2] = _t; } \
    if (t8[1] < t8[0]) { _t = t8[0]; t8[0] = t8[1]; t8[1] = _t; } \
  } while (0)

// ---------------- Kernel 1: xx[row] = sum_d x^2 ----------------
__global__ __launch_bounds__(256) void k_xx(const float* __restrict__ x,
                                            float* __restrict__ xx) {
  int row  = blockIdx.x * 4 + (threadIdx.x >> 6);
  int lane = threadIdx.x & 63;
  float2 v = *reinterpret_cast<const float2*>(x + (size_t)row * DD + lane * 2);
  float p = v.x * v.x + v.y * v.y;
  #pragma unroll
  for (int off = 1; off < 64; off <<= 1) p += __shfl_xor(p, off);
  if (lane == 0) xx[row] = p;
}

// ---------------- Kernel 2: dual GEMM  s = x@Ws, y = x@Wn ----------------
__global__ __launch_bounds__(256) void k_gemm(const float* __restrict__ x,
                                              const float* __restrict__ Ws,
                                              const float* __restrict__ Wn,
                                              const float* __restrict__ bias,
                                              float* __restrict__ hbase,
                                              float* __restrict__ y) {
  __shared__ __align__(16) float xt[128 * 64];    // [k][r]
  __shared__ __align__(16) float wt[128 * 128];   // [k][c]
  int tid = threadIdx.x;
  size_t r0 = (size_t)blockIdx.x * 64;

  { // stage x transposed
    int rr = tid >> 2, kp = (tid & 3) << 5;
    const float* src = x + (r0 + rr) * DD + kp;
    #pragma unroll
    for (int q = 0; q < 8; ++q) {
      float4 v = *(const float4*)(src + (q << 2));
      int k = kp + (q << 2);
      xt[(k + 0) * 64 + rr] = v.x; xt[(k + 1) * 64 + rr] = v.y;
      xt[(k + 2) * 64 + rr] = v.z; xt[(k + 3) * 64 + rr] = v.w;
    }
  }
  { // stage Ws (row-major copy)
    const float4* s4 = (const float4*)Ws;
    float4* w4 = (float4*)wt;
    #pragma unroll
    for (int q = 0; q < 16; ++q) w4[q * 256 + tid] = s4[q * 256 + tid];
  }
  __syncthreads();

  int tc = tid & 15, tr = tid >> 4;
  float accS[4][8], accY[4][8];
  #pragma unroll
  for (int i = 0; i < 4; ++i)
    #pragma unroll
    for (int u = 0; u < 8; ++u) { accS[i][u] = 0.f; accY[i][u] = 0.f; }

  #pragma unroll 2
  for (int k = 0; k < 128; ++k) {
    float4 a4 = *(const float4*)(xt + k * 64 + (tr << 2));
    float4 w0 = *(const float4*)(wt + k * 128 + (tc << 3));
    float4 w1 = *(const float4*)(wt + k * 128 + (tc << 3) + 4);
    float aa[4] = {a4.x, a4.y, a4.z, a4.w};
    float ww[8] = {w0.x, w0.y, w0.z, w0.w, w1.x, w1.y, w1.z, w1.w};
    #pragma unroll
    for (int i = 0; i < 4; ++i)
      #pragma unroll
      for (int u = 0; u < 8; ++u) accS[i][u] = fmaf(aa[i], ww[u], accS[i][u]);
  }
  __syncthreads();
  { // stage Wn
    const float4* s4 = (const float4*)Wn;
    float4* w4 = (float4*)wt;
    #pragma unroll
    for (int q = 0; q < 16; ++q) w4[q * 256 + tid] = s4[q * 256 + tid];
  }
  __syncthreads();
  #pragma unroll 2
  for (int k = 0; k < 128; ++k) {
    float4 a4 = *(const float4*)(xt + k * 64 + (tr << 2));
    float4 w0 = *(const float4*)(wt + k * 128 + (tc << 3));
    float4 w1 = *(const float4*)(wt + k * 128 + (tc << 3) + 4);
    float aa[4] = {a4.x, a4.y, a4.z, a4.w};
    float ww[8] = {w0.x, w0.y, w0.z, w0.w, w1.x, w1.y, w1.z, w1.w};
    #pragma unroll
    for (int i = 0; i < 4; ++i)
      #pragma unroll
      for (int u = 0; u < 8; ++u) accY[i][u] = fmaf(aa[i], ww[u], accY[i][u]);
  }

  float4 bv0 = *(const float4*)(bias + (tc << 3));
  float4 bv1 = *(const float4*)(bias + (tc << 3) + 4);
  float bb[8] = {bv0.x, bv0.y, bv0.z, bv0.w, bv1.x, bv1.y, bv1.z, bv1.w};
  #pragma unroll
  for (int i = 0; i < 4; ++i) {
    size_t row = r0 + (tr << 2) + i;
    float h[8];
    #pragma unroll
    for (int u = 0; u < 8; ++u) h[u] = (accS[i][u] + accY[i][u]) + bb[u];
    *(float4*)(y + row * DD + (tc << 3))     = make_float4(accY[i][0], accY[i][1], accY[i][2], accY[i][3]);
    *(float4*)(y + row * DD + (tc << 3) + 4) = make_float4(accY[i][4], accY[i][5], accY[i][6], accY[i][7]);
    *(float4*)(hbase + row * DD + (tc << 3))     = make_float4(h[0], h[1], h[2], h[3]);
    *(float4*)(hbase + row * DD + (tc << 3) + 4) = make_float4(h[4], h[5], h[6], h[7]);
  }
}

// ---------------- Kernel 3: pairwise dist + 8-NN selection ----------------
// grid 256 = 8 batches x 32 n-tiles(64). block 256 (4 waves).
// m-tile 256, k-chunked (32) Bt staging with register prefetch.
// thread tile 8n x 8m; per-lane LDS accesses are CONSECUTIVE 16B chunks
// (conflict-free within b128 data phases); A-reads are broadcast.
__global__ __launch_bounds__(256) void k_knn(const float* __restrict__ x,
                                             const float* __restrict__ xx,
                                             int* __restrict__ nbr) {
  __shared__ __align__(16) float At[128 * 64];     // [k][n]        32.0 KB
  __shared__ __align__(16) float Bt[32 * 264];     // [k-chunk][m]  33.8 KB
  __shared__ __align__(16) float Dd[64 * 264];     // [n][m]        67.6 KB
  __shared__ float xxn[64];
  __shared__ float xxm[256];

  int tid = threadIdx.x;
  int b  = blockIdx.x >> 5;
  int n0 = (blockIdx.x & 31) << 6;
  const float* xb  = x  + ((size_t)b << 11) * DD;
  const float* xxb = xx + ((size_t)b << 11);

  { // stage A transposed: lanes write consecutive columns (2-way banks, free)
    int rr = tid & 63, kp = (tid >> 6) << 5;
    const float* src = xb + (size_t)(n0 + rr) * DD + kp;
    #pragma unroll
    for (int q = 0; q < 8; ++q) {
      float4 v = *(const float4*)(src + (q << 2));
      int k = kp + (q << 2);
      At[(k + 0) * 64 + rr] = v.x; At[(k + 1) * 64 + rr] = v.y;
      At[(k + 2) * 64 + rr] = v.z; At[(k + 3) * 64 + rr] = v.w;
    }
  }
  if (tid < 64) xxn[tid] = xxb[n0 + tid];

  int tc = tid & 31, tr = tid >> 5;       // compute: rows tr*8+i, cols {tc*4+j, 128+tc*4+j}
  int srow = tid >> 2, sj = tid & 3;      // scan: 4 scanners/row, float4 chunks
  int my_n = n0 + srow;

  ull t8[8];
  #pragma unroll
  for (int q = 0; q < 8; ++q) t8[q] = ~0ull;

  // prefetch (mt=0, kc=0): thread owns m-row `tid` of the tile
  float4 bpre[8];
  {
    const float* bs = xb + (size_t)tid * DD;
    #pragma unroll
    for (int q = 0; q < 8; ++q) bpre[q] = *(const float4*)(bs + (q << 2));
  }
  float xmreg = xxb[tid];

  for (int mt = 0; mt < 8; ++mt) {
    int m0 = mt << 8;

    float acc[8][8];
    #pragma unroll
    for (int i = 0; i < 8; ++i)
      #pragma unroll
      for (int u = 0; u < 8; ++u) acc[i][u] = 0.f;

    for (int kc = 0; kc < 4; ++kc) {
      if (kc) __syncthreads();            // prev compute done reading Bt
      // write Bt chunk: lanes write consecutive columns at same k -> 2-way, free
      #pragma unroll
      for (int q = 0; q < 8; ++q) {
        int k = q << 2;
        Bt[(k + 0) * 264 + tid] = bpre[q].x; Bt[(k + 1) * 264 + tid] = bpre[q].y;
        Bt[(k + 2) * 264 + tid] = bpre[q].z; Bt[(k + 3) * 264 + tid] = bpre[q].w;
      }
      if (kc == 0) xxm[tid] = xmreg;
      // issue next-chunk global loads (complete during compute)
      if (!(mt == 7 && kc == 3)) {
        int nmt = (kc == 3) ? mt + 1 : mt;
        int nkc = (kc == 3) ? 0 : kc + 1;
        const float* ns = xb + (size_t)((nmt << 8) + tid) * DD + (nkc << 5);
        #pragma unroll
        for (int q = 0; q < 8; ++q) bpre[q] = *(const float4*)(ns + (q << 2));
        if (kc == 3) xmreg = xxb[(nmt << 8) + tid];
      }
      __syncthreads();                    // Bt ready

      const float* Ab = At + ((kc << 5) * 64) + (tr << 3);
      const float* Bb = Bt + (tc << 2);
      #pragma unroll 4
      for (int k = 0; k < 32; ++k) {
        float4 a0 = *(const float4*)(Ab + k * 64);
        float4 a1 = *(const float4*)(Ab + k * 64 + 4);
        float4 b0 = *(const float4*)(Bb + k * 264);
        float4 b1 = *(const float4*)(Bb + k * 264 + 128);
        float aa[8]  = {a0.x, a0.y, a0.z, a0.w, a1.x, a1.y, a1.z, a1.w};
        float bbv[8] = {b0.x, b0.y, b0.z, b0.w, b1.x, b1.y, b1.z, b1.w};
        #pragma unroll
        for (int i = 0; i < 8; ++i)
          #pragma unroll
          for (int u = 0; u < 8; ++u) acc[i][u] = fmaf(aa[i], bbv[u], acc[i][u]);
      }
    }

    // dist = (xx_n - 2*dot) + xx_m, clipped; write to Dd (consecutive chunks)
    float4 xn0 = *(const float4*)(xxn + (tr << 3));
    float4 xn1 = *(const float4*)(xxn + (tr << 3) + 4);
    float4 xm0 = *(const float4*)(xxm + (tc << 2));
    float4 xm1 = *(const float4*)(xxm + 128 + (tc << 2));
    float xnv[8] = {xn0.x, xn0.y, xn0.z, xn0.w, xn1.x, xn1.y, xn1.z, xn1.w};
    float xlo[4] = {xm0.x, xm0.y, xm0.z, xm0.w};
    float xhi[4] = {xm1.x, xm1.y, xm1.z, xm1.w};
    #pragma unroll
    for (int i = 0; i < 8; ++i) {
      float4 d0, d1;
      d0.x = fmaxf((xnv[i] - 2.f * acc[i][0]) + xlo[0], 0.f);
      d0.y = fmaxf((xnv[i] - 2.f * acc[i][1]) + xlo[1], 0.f);
      d0.z = fmaxf((xnv[i] - 2.f * acc[i][2]) + xlo[2], 0.f);
      d0.w = fmaxf((xnv[i] - 2.f * acc[i][3]) + xlo[3], 0.f);
      d1.x = fmaxf((xnv[i] - 2.f * acc[i][4]) + xhi[0], 0.f);
      d1.y = fmaxf((xnv[i] - 2.f * acc[i][5]) + xhi[1], 0.f);
      d1.z = fmaxf((xnv[i] - 2.f * acc[i][6]) + xhi[2], 0.f);
      d1.w = fmaxf((xnv[i] - 2.f * acc[i][7]) + xhi[3], 0.f);
      int row = (tr << 3) + i;
      *(float4*)(Dd + row * 264 + (tc << 2))       = d0;
      *(float4*)(Dd + row * 264 + 128 + (tc << 2)) = d1;
    }
    __syncthreads();   // Dd ready

    // scan: scanner sj reads float4 chunks sj, sj+4, sj+8, ... (16 chunks)
    const float* dbase = Dd + srow * 264 + (sj << 2);
    #pragma unroll 4
    for (int t = 0; t < 16; ++t) {
      float4 dv = *(const float4*)(dbase + (t << 4));
      int mg0 = m0 + ((sj + (t << 2)) << 2);
      float dc[4] = {dv.x, dv.y, dv.z, dv.w};
      #pragma unroll
      for (int e = 0; e < 4; ++e) {
        int mg = mg0 + e;
        ull cand = (((ull)__float_as_uint(dc[e])) << 32) | (unsigned)mg;
        if (mg != my_n && cand < t8[7]) INS8(t8, cand);
      }
    }
    // no sync needed here: Dd is not rewritten until after multiple barriers
  }

  __syncthreads();   // all scans done before mbuf overwrites Dd
  ull* mbuf = (ull*)Dd;  // 64 rows * 4 lists * 8 u64 = 16 KB <= Dd
  #pragma unroll
  for (int q = 0; q < 8; ++q) mbuf[((srow << 2) + sj) * 8 + q] = t8[q];
  __syncthreads();
  if (sj == 0) {
    for (int j = 1; j < 4; ++j) {
      #pragma unroll
      for (int q = 0; q < 8; ++q) {
        ull cand = mbuf[((srow << 2) + j) * 8 + q];
        if (cand < t8[7]) INS8(t8, cand);
      }
    }
    int* op = nbr + (((size_t)b << 11) + my_n) * 8;
    #pragma unroll
    for (int q = 0; q < 8; ++q) op[q] = (int)(t8[q] & 0xffffffffu);
  }
}

// ---------------- Kernel 4: gather + KAN rational + BN partial sums ----------------
__global__ __launch_bounds__(256) void k_kan(const float* __restrict__ hbase,
                                             const float* __restrict__ y,
                                             const int* __restrict__ nbr,
                                             const float* __restrict__ kan_a,
                                             const float* __restrict__ kan_b,
                                             float* __restrict__ hkan,
                                             double* __restrict__ sums) {
  int f = threadIdx.x & 127;
  int half = threadIdx.x >> 7;
  int r0 = blockIdx.x * 16 + half * 8;
  float a0 = kan_a[f * 3 + 0], a1 = kan_a[f * 3 + 1], a2 = kan_a[f * 3 + 2];
  float b0 = kan_b[f * 2 + 0], b1 = kan_b[f * 2 + 1];
  float disf = (float)(1.0 / sqrt((double)(8.0f + 1e-6f)));
  float cf = disf * disf;
  double sh = 0.0, sh2 = 0.0;
  #pragma unroll
  for (int i = 0; i < 8; ++i) {
    int r = r0 + i;
    int bb = r >> 11;
    const int* np_ = nbr + (size_t)r * 8;
    float t = 0.f;
    #pragma unroll
    for (int j = 0; j < 8; ++j) {
      int m = np_[j];
      float yv = y[((size_t)(bb << 11) + m) * DD + f];
      t = fmaf(cf, yv, t);
    }
    float h = hbase[(size_t)r * DD + f] + t;
    float h2 = h * h;
    float num = (a0 + a1 * h) + a2 * h2;
    float den = 1.0f + fabsf(b0 * h + b1 * h2);
    float hk = num / (den + 1e-8f);
    hkan[(size_t)r * DD + f] = hk;
    sh += (double)hk; sh2 += (double)hk * (double)hk;
  }
  atomicAdd(&sums[f], sh);
  atomicAdd(&sums[128 + f], sh2);
}

// ---------------- Kernel 5: BN finalize + normalize ----------------
__global__ __launch_bounds__(256) void k_bn(const float* __restrict__ hkan,
                                            const double* __restrict__ sums,
                                            const float* __restrict__ gamma,
                                            const float* __restrict__ beta,
                                            float* __restrict__ out) {
  __shared__ float mn[128], sc[128], bt[128];
  int tid = threadIdx.x;
  if (tid < 128) {
    double M = (double)(BB * NN);
    double mean = sums[tid] / M;
    double var = sums[128 + tid] / M - mean * mean;
    if (var < 0.0) var = 0.0;
    mn[tid] = (float)mean;
    sc[tid] = (float)(1.0 / sqrt(var + 1e-5)) * gamma[tid];
    bt[tid] = beta[tid];
  }
  __syncthreads();
  const int total4 = BB * NN * DD / 4;
  for (int i4 = blockIdx.x * blockDim.x + threadIdx.x; i4 < total4;
       i4 += gridDim.x * blockDim.x) {
    float4 v = ((const float4*)hkan)[i4];
    int fb = (i4 * 4) & 127;
    float4 o;
    o.x = (v.x - mn[fb + 0]) * sc[fb + 0] + bt[fb + 0];
    o.y = (v.y - mn[fb + 1]) * sc[fb + 1] + bt[fb + 1];
    o.z = (v.z - mn[fb + 2]) * sc[fb + 2] + bt[fb + 2];
    o.w = (v.w - mn[fb + 3]) * sc[fb + 3] + bt[fb + 3];
    ((float4*)out)[i4] = o;
  }
}

extern "C" void kernel_launch(void* const* d_in, const int* in_sizes, int n_in,
                              void* d_out, int out_size, void* d_ws, size_t ws_size,
                              hipStream_t stream) {
  const float* x     = (const float*)d_in[0];
  const float* Ws    = (const float*)d_in[1];
  const float* Wn    = (const float*)d_in[2];
  const float* ka    = (const float*)d_in[3];
  const float* kb    = (const float*)d_in[4];
  const float* bias  = (const float*)d_in[5];
  const float* gamma = (const float*)d_in[6];
  const float* beta  = (const float*)d_in[7];
  float* out = (float*)d_out;

  char* ws = (char*)d_ws;
  float*  xx    = (float*)(ws + 0);          //  64 KB
  int*    nbr   = (int*)(ws + 65536);        // 512 KB
  double* sums  = (double*)(ws + 589824);    //   2 KB
  float*  y     = (float*)(ws + 1048576);    //   8 MB
  float*  hbase = (float*)(ws + 9437184);    //   8 MB
  float*  hkan  = (float*)(ws + 17825792);   //   8 MB

  hipMemsetAsync(sums, 0, 256 * sizeof(double), stream);
  k_xx  <<<4096, 256, 0, stream>>>(x, xx);
  k_gemm<<<256,  256, 0, stream>>>(x, Ws, Wn, bias, hbase, y);
  k_knn <<<256,  256, 0, stream>>>(x, xx, nbr);
  k_kan <<<1024, 256, 0, stream>>>(hbase, y, nbr, ka, kb, hkan, sums);
  k_bn  <<<1024, 256, 0, stream>>>(hkan, sums, gamma, beta, out);
}

// Round 4
// 280.651 us; speedup vs baseline: 1.2431x; 1.2431x over previous
//
#include <hip/hip_runtime.h>
#include <stdint.h>

#define BB 8
#define NN 2048
#define DD 128

typedef unsigned long long ull;

// insertion into sorted-ascending 8-slot register array (static indices only)
#define INS8(t8, cand) do { \
    t8[7] = (cand); ull _t; \
    if (t8[7] < t8[6]) { _t = t8[6]; t8[6] = t8[7]; t8[7] = _t; } \
    if (t8[6] < t8[5]) { _t = t8[5]; t8[5] = t8[6]; t8[6] = _t; } \
    if (t8[5] < t8[4]) { _t = t8[4]; t8[4] = t8[5]; t8[5] = _t; } \
    if (t8[4] < t8[3]) { _t = t8[3]; t8[3] = t8[4]; t8[4] = _t; } \
    if (t8[3] < t8[2]) { _t = t8[2]; t8[2] = t8[3]; t8[3] = _t; } \
    if (t8[2] < t8[1]) { _t = t8[1]; t8[1] = t8[2]; t8[2] = _t; } \
    if (t8[1] < t8[0]) { _t = t8[0]; t8[0] = t8[1]; t8[1] = _t; } \
  } while (0)

// ---------------- Kernel 1: xx[row] = sum_d x^2 ----------------
__global__ __launch_bounds__(256) void k_xx(const float* __restrict__ x,
                                            float* __restrict__ xx) {
  int row  = blockIdx.x * 4 + (threadIdx.x >> 6);
  int lane = threadIdx.x & 63;
  float2 v = *reinterpret_cast<const float2*>(x + (size_t)row * DD + lane * 2);
  float p = v.x * v.x + v.y * v.y;
  #pragma unroll
  for (int off = 1; off < 64; off <<= 1) p += __shfl_xor(p, off);
  if (lane == 0) xx[row] = p;
}

// ---------------- Kernel 2: dual GEMM  s = x@Ws, y = x@Wn ----------------
__global__ __launch_bounds__(256) void k_gemm(const float* __restrict__ x,
                                              const float* __restrict__ Ws,
                                              const float* __restrict__ Wn,
                                              const float* __restrict__ bias,
                                              float* __restrict__ hbase,
                                              float* __restrict__ y) {
  __shared__ __align__(16) float xt[128 * 64];    // [k][r]
  __shared__ __align__(16) float wt[128 * 128];   // [k][c]
  int tid = threadIdx.x;
  size_t r0 = (size_t)blockIdx.x * 64;

  { // stage x transposed
    int rr = tid >> 2, kp = (tid & 3) << 5;
    const float* src = x + (r0 + rr) * DD + kp;
    #pragma unroll
    for (int q = 0; q < 8; ++q) {
      float4 v = *(const float4*)(src + (q << 2));
      int k = kp + (q << 2);
      xt[(k + 0) * 64 + rr] = v.x; xt[(k + 1) * 64 + rr] = v.y;
      xt[(k + 2) * 64 + rr] = v.z; xt[(k + 3) * 64 + rr] = v.w;
    }
  }
  { // stage Ws (row-major copy)
    const float4* s4 = (const float4*)Ws;
    float4* w4 = (float4*)wt;
    #pragma unroll
    for (int q = 0; q < 16; ++q) w4[q * 256 + tid] = s4[q * 256 + tid];
  }
  __syncthreads();

  int tc = tid & 15, tr = tid >> 4;
  float accS[4][8], accY[4][8];
  #pragma unroll
  for (int i = 0; i < 4; ++i)
    #pragma unroll
    for (int u = 0; u < 8; ++u) { accS[i][u] = 0.f; accY[i][u] = 0.f; }

  #pragma unroll 2
  for (int k = 0; k < 128; ++k) {
    float4 a4 = *(const float4*)(xt + k * 64 + (tr << 2));
    float4 w0 = *(const float4*)(wt + k * 128 + (tc << 2));
    float4 w1 = *(const float4*)(wt + k * 128 + 64 + (tc << 2));
    float aa[4] = {a4.x, a4.y, a4.z, a4.w};
    float ww[8] = {w0.x, w0.y, w0.z, w0.w, w1.x, w1.y, w1.z, w1.w};
    #pragma unroll
    for (int i = 0; i < 4; ++i)
      #pragma unroll
      for (int u = 0; u < 8; ++u) accS[i][u] = fmaf(aa[i], ww[u], accS[i][u]);
  }
  __syncthreads();
  { // stage Wn
    const float4* s4 = (const float4*)Wn;
    float4* w4 = (float4*)wt;
    #pragma unroll
    for (int q = 0; q < 16; ++q) w4[q * 256 + tid] = s4[q * 256 + tid];
  }
  __syncthreads();
  #pragma unroll 2
  for (int k = 0; k < 128; ++k) {
    float4 a4 = *(const float4*)(xt + k * 64 + (tr << 2));
    float4 w0 = *(const float4*)(wt + k * 128 + (tc << 2));
    float4 w1 = *(const float4*)(wt + k * 128 + 64 + (tc << 2));
    float aa[4] = {a4.x, a4.y, a4.z, a4.w};
    float ww[8] = {w0.x, w0.y, w0.z, w0.w, w1.x, w1.y, w1.z, w1.w};
    #pragma unroll
    for (int i = 0; i < 4; ++i)
      #pragma unroll
      for (int u = 0; u < 8; ++u) accY[i][u] = fmaf(aa[i], ww[u], accY[i][u]);
  }

  // columns owned: c0 = tc*4 .. +3 and c1 = 64 + tc*4 .. +3
  float4 bv0 = *(const float4*)(bias + (tc << 2));
  float4 bv1 = *(const float4*)(bias + 64 + (tc << 2));
  float bb[8] = {bv0.x, bv0.y, bv0.z, bv0.w, bv1.x, bv1.y, bv1.z, bv1.w};
  #pragma unroll
  for (int i = 0; i < 4; ++i) {
    size_t row = r0 + (tr << 2) + i;
    float h[8];
    #pragma unroll
    for (int u = 0; u < 8; ++u) h[u] = (accS[i][u] + accY[i][u]) + bb[u];
    *(float4*)(y + row * DD + (tc << 2))      = make_float4(accY[i][0], accY[i][1], accY[i][2], accY[i][3]);
    *(float4*)(y + row * DD + 64 + (tc << 2)) = make_float4(accY[i][4], accY[i][5], accY[i][6], accY[i][7]);
    *(float4*)(hbase + row * DD + (tc << 2))      = make_float4(h[0], h[1], h[2], h[3]);
    *(float4*)(hbase + row * DD + 64 + (tc << 2)) = make_float4(h[4], h[5], h[6], h[7]);
  }
}

// ---------------- Kernel 3: pairwise dist + 8-NN selection ----------------
// grid 256 = 8 batches x 32 n-tiles(64). block 512 (8 waves, 2/SIMD).
// m-tile 256, k-chunked (32) Bt staging with register prefetch chain.
// thread tile 4n x 8m, m-cols split {tc*4, 128+tc*4}: every hot LDS access is
// per-lane-consecutive-16B-chunks (conflict-free); A-reads broadcast.
__global__ __launch_bounds__(512) void k_knn(const float* __restrict__ x,
                                             const float* __restrict__ xx,
                                             int* __restrict__ nbr) {
  __shared__ __align__(16) float At[128 * 64];     // [k][n]        32.0 KB
  __shared__ __align__(16) float Bt[32 * 264];     // [k-chunk][m]  33.8 KB
  __shared__ __align__(16) float Dd[64 * 264];     // [n][m]        67.6 KB
  __shared__ float xxn[64];
  __shared__ float xxm[256];

  int tid = threadIdx.x;
  int b  = blockIdx.x >> 5;
  int n0 = (blockIdx.x & 31) << 6;
  const float* xb  = x  + ((size_t)b << 11) * DD;
  const float* xxb = xx + ((size_t)b << 11);

  { // stage A transposed: lanes write consecutive columns (2-way banks, free)
    int rr = tid & 63, kp = (tid >> 6) << 4;
    const float* src = xb + (size_t)(n0 + rr) * DD + kp;
    #pragma unroll
    for (int q = 0; q < 4; ++q) {
      float4 v = *(const float4*)(src + (q << 2));
      int k = kp + (q << 2);
      At[(k + 0) * 64 + rr] = v.x; At[(k + 1) * 64 + rr] = v.y;
      At[(k + 2) * 64 + rr] = v.z; At[(k + 3) * 64 + rr] = v.w;
    }
  }
  if (tid < 64) xxn[tid] = xxb[n0 + tid];

  int tc = tid & 31, tr = tid >> 5;        // compute: rows tr*4+i, cols {tc*4+j, 128+tc*4+j}
  int srow = tid >> 3, sj = tid & 7;       // scan: 8 scanners/row, scalar stride-8
  int my_n = n0 + srow;
  int mrr = tid >> 1, kq = (tid & 1) << 4; // Bt staging: 2 threads/row, 16 k each

  ull t8[8];
  #pragma unroll
  for (int q = 0; q < 8; ++q) t8[q] = ~0ull;

  // prefetch (mt=0, kc=0)
  float4 bpre[4];
  {
    const float* bs = xb + (size_t)mrr * DD + kq;
    #pragma unroll
    for (int q = 0; q < 4; ++q) bpre[q] = *(const float4*)(bs + (q << 2));
  }
  float xmreg = (tid < 256) ? xxb[tid] : 0.f;

  for (int mt = 0; mt < 8; ++mt) {
    int m0 = mt << 8;

    float acc[4][8];
    #pragma unroll
    for (int i = 0; i < 4; ++i)
      #pragma unroll
      for (int u = 0; u < 8; ++u) acc[i][u] = 0.f;

    for (int kc = 0; kc < 4; ++kc) {
      __syncthreads();   // prev compute done reading Bt (and scan of prev Dd done)
      // write Bt chunk: at each step lanes write consecutive columns -> 2-way, free
      #pragma unroll
      for (int q = 0; q < 4; ++q) {
        int k = kq + (q << 2);
        Bt[(k + 0) * 264 + mrr] = bpre[q].x; Bt[(k + 1) * 264 + mrr] = bpre[q].y;
        Bt[(k + 2) * 264 + mrr] = bpre[q].z; Bt[(k + 3) * 264 + mrr] = bpre[q].w;
      }
      if (kc == 0 && tid < 256) xxm[tid] = xmreg;
      // issue next-chunk global loads (complete during compute)
      if (!(mt == 7 && kc == 3)) {
        int nmt = (kc == 3) ? mt + 1 : mt;
        int nkc = (kc + 1) & 3;
        const float* ns = xb + (size_t)((nmt << 8) + mrr) * DD + (nkc << 5) + kq;
        #pragma unroll
        for (int q = 0; q < 4; ++q) bpre[q] = *(const float4*)(ns + (q << 2));
        if (kc == 3 && tid < 256) xmreg = xxb[(nmt << 8) + tid];
      }
      __syncthreads();   // Bt ready

      const float* Ab = At + ((kc << 5) * 64) + (tr << 2);
      const float* Bb = Bt + (tc << 2);
      #pragma unroll 4
      for (int k = 0; k < 32; ++k) {
        float4 a4 = *(const float4*)(Ab + k * 64);
        float4 b0 = *(const float4*)(Bb + k * 264);
        float4 b1 = *(const float4*)(Bb + k * 264 + 128);
        float aa[4]  = {a4.x, a4.y, a4.z, a4.w};
        float bbv[8] = {b0.x, b0.y, b0.z, b0.w, b1.x, b1.y, b1.z, b1.w};
        #pragma unroll
        for (int i = 0; i < 4; ++i)
          #pragma unroll
          for (int u = 0; u < 8; ++u) acc[i][u] = fmaf(aa[i], bbv[u], acc[i][u]);
      }
    }

    // dist = (xx_n - 2*dot) + xx_m, clipped; write Dd as consecutive chunks
    float4 xn4 = *(const float4*)(xxn + (tr << 2));
    float4 xm0 = *(const float4*)(xxm + (tc << 2));
    float4 xm1 = *(const float4*)(xxm + 128 + (tc << 2));
    float xnv[4] = {xn4.x, xn4.y, xn4.z, xn4.w};
    float xlo[4] = {xm0.x, xm0.y, xm0.z, xm0.w};
    float xhi[4] = {xm1.x, xm1.y, xm1.z, xm1.w};
    #pragma unroll
    for (int i = 0; i < 4; ++i) {
      float4 d0, d1;
      d0.x = fmaxf((xnv[i] - 2.f * acc[i][0]) + xlo[0], 0.f);
      d0.y = fmaxf((xnv[i] - 2.f * acc[i][1]) + xlo[1], 0.f);
      d0.z = fmaxf((xnv[i] - 2.f * acc[i][2]) + xlo[2], 0.f);
      d0.w = fmaxf((xnv[i] - 2.f * acc[i][3]) + xlo[3], 0.f);
      d1.x = fmaxf((xnv[i] - 2.f * acc[i][4]) + xhi[0], 0.f);
      d1.y = fmaxf((xnv[i] - 2.f * acc[i][5]) + xhi[1], 0.f);
      d1.z = fmaxf((xnv[i] - 2.f * acc[i][6]) + xhi[2], 0.f);
      d1.w = fmaxf((xnv[i] - 2.f * acc[i][7]) + xhi[3], 0.f);
      int row = (tr << 2) + i;
      *(float4*)(Dd + row * 264 + (tc << 2))       = d0;
      *(float4*)(Dd + row * 264 + 128 + (tc << 2)) = d1;
    }
    __syncthreads();   // Dd ready

    // scan: scanner sj reads cols sj + 8t (bank = 8*srow + sj + 8t -> 2-way, free)
    const float* dbase = Dd + srow * 264 + sj;
    #pragma unroll 8
    for (int t = 0; t < 32; ++t) {
      float d = dbase[t << 3];
      int mg = m0 + sj + (t << 3);
      ull cand = (((ull)__float_as_uint(d)) << 32) | (unsigned)mg;
      if (mg != my_n && cand < t8[7]) INS8(t8, cand);
    }
    // next Dd write is 8 barriers away; next Bt write guarded by top-of-loop barrier
  }

  __syncthreads();   // all scans done before mbuf overwrites Dd
  ull* mbuf = (ull*)Dd;  // 64 rows * 8 lists * 8 u64 = 32 KB <= Dd
  #pragma unroll
  for (int q = 0; q < 8; ++q) mbuf[((srow << 3) + sj) * 8 + q] = t8[q];
  __syncthreads();
  if (sj == 0) {
    for (int j = 1; j < 8; ++j) {
      #pragma unroll
      for (int q = 0; q < 8; ++q) {
        ull cand = mbuf[((srow << 3) + j) * 8 + q];
        if (cand < t8[7]) INS8(t8, cand);
      }
    }
    int* op = nbr + (((size_t)b << 11) + my_n) * 8;
    #pragma unroll
    for (int q = 0; q < 8; ++q) op[q] = (int)(t8[q] & 0xffffffffu);
  }
}

// ---------------- Kernel 4: gather + KAN rational + BN partial sums ----------------
__global__ __launch_bounds__(256) void k_kan(const float* __restrict__ hbase,
                                             const float* __restrict__ y,
                                             const int* __restrict__ nbr,
                                             const float* __restrict__ kan_a,
                                             const float* __restrict__ kan_b,
                                             float* __restrict__ hkan,
                                             double* __restrict__ sums) {
  int f = threadIdx.x & 127;
  int half = threadIdx.x >> 7;
  int r0 = blockIdx.x * 16 + half * 8;
  float a0 = kan_a[f * 3 + 0], a1 = kan_a[f * 3 + 1], a2 = kan_a[f * 3 + 2];
  float b0 = kan_b[f * 2 + 0], b1 = kan_b[f * 2 + 1];
  float disf = (float)(1.0 / sqrt((double)(8.0f + 1e-6f)));
  float cf = disf * disf;
  double sh = 0.0, sh2 = 0.0;
  #pragma unroll
  for (int i = 0; i < 8; ++i) {
    int r = r0 + i;
    int bb = r >> 11;
    const int* np_ = nbr + (size_t)r * 8;
    float t = 0.f;
    #pragma unroll
    for (int j = 0; j < 8; ++j) {
      int m = np_[j];
      float yv = y[((size_t)(bb << 11) + m) * DD + f];
      t = fmaf(cf, yv, t);
    }
    float h = hbase[(size_t)r * DD + f] + t;
    float h2 = h * h;
    float num = (a0 + a1 * h) + a2 * h2;
    float den = 1.0f + fabsf(b0 * h + b1 * h2);
    float hk = num / (den + 1e-8f);
    hkan[(size_t)r * DD + f] = hk;
    sh += (double)hk; sh2 += (double)hk * (double)hk;
  }
  atomicAdd(&sums[f], sh);
  atomicAdd(&sums[128 + f], sh2);
}

// ---------------- Kernel 5: BN finalize + normalize ----------------
__global__ __launch_bounds__(256) void k_bn(const float* __restrict__ hkan,
                                            const double* __restrict__ sums,
                                            const float* __restrict__ gamma,
                                            const float* __restrict__ beta,
                                            float* __restrict__ out) {
  __shared__ float mn[128], sc[128], bt[128];
  int tid = threadIdx.x;
  if (tid < 128) {
    double M = (double)(BB * NN);
    double mean = sums[tid] / M;
    double var = sums[128 + tid] / M - mean * mean;
    if (var < 0.0) var = 0.0;
    mn[tid] = (float)mean;
    sc[tid] = (float)(1.0 / sqrt(var + 1e-5)) * gamma[tid];
    bt[tid] = beta[tid];
  }
  __syncthreads();
  const int total4 = BB * NN * DD / 4;
  for (int i4 = blockIdx.x * blockDim.x + threadIdx.x; i4 < total4;
       i4 += gridDim.x * blockDim.x) {
    float4 v = ((const float4*)hkan)[i4];
    int fb = (i4 * 4) & 127;
    float4 o;
    o.x = (v.x - mn[fb + 0]) * sc[fb + 0] + bt[fb + 0];
    o.y = (v.y - mn[fb + 1]) * sc[fb + 1] + bt[fb + 1];
    o.z = (v.z - mn[fb + 2]) * sc[fb + 2] + bt[fb + 2];
    o.w = (v.w - mn[fb + 3]) * sc[fb + 3] + bt[fb + 3];
    ((float4*)out)[i4] = o;
  }
}

extern "C" void kernel_launch(void* const* d_in, const int* in_sizes, int n_in,
                              void* d_out, int out_size, void* d_ws, size_t ws_size,
                              hipStream_t stream) {
  const float* x     = (const float*)d_in[0];
  const float* Ws    = (const float*)d_in[1];
  const float* Wn    = (const float*)d_in[2];
  const float* ka    = (const float*)d_in[3];
  const float* kb    = (const float*)d_in[4];
  const float* bias  = (const float*)d_in[5];
  const float* gamma = (const float*)d_in[6];
  const float* beta  = (const float*)d_in[7];
  float* out = (float*)d_out;

  char* ws = (char*)d_ws;
  float*  xx    = (float*)(ws + 0);          //  64 KB
  int*    nbr   = (int*)(ws + 65536);        // 512 KB
  double* sums  = (double*)(ws + 589824);    //   2 KB
  float*  y     = (float*)(ws + 1048576);    //   8 MB
  float*  hbase = (float*)(ws + 9437184);    //   8 MB
  float*  hkan  = (float*)(ws + 17825792);   //   8 MB

  hipMemsetAsync(sums, 0, 256 * sizeof(double), stream);
  k_xx  <<<4096, 256, 0, stream>>>(x, xx);
  k_gemm<<<256,  256, 0, stream>>>(x, Ws, Wn, bias, hbase, y);
  k_knn <<<256,  512, 0, stream>>>(x, xx, nbr);
  k_kan <<<1024, 256, 0, stream>>>(hbase, y, nbr, ka, kb, hkan, sums);
  k_bn  <<<1024, 256, 0, stream>>>(hkan, sums, gamma, beta, out);
}

// Round 5
// 240.831 us; speedup vs baseline: 1.4487x; 1.1653x over previous
//
#include <hip/hip_runtime.h>
#include <stdint.h>

#define BB 8
#define NN 2048
#define DD 128

typedef unsigned long long ull;

// insertion into sorted-ascending 8-slot register array (static indices only)
#define INS8(t8, cand) do { \
    t8[7] = (cand); ull _t; \
    if (t8[7] < t8[6]) { _t = t8[6]; t8[6] = t8[7]; t8[7] = _t; } \
    if (t8[6] < t8[5]) { _t = t8[5]; t8[5] = t8[6]; t8[6] = _t; } \
    if (t8[5] < t8[4]) { _t = t8[4]; t8[4] = t8[5]; t8[5] = _t; } \
    if (t8[4] < t8[3]) { _t = t8[3]; t8[3] = t8[4]; t8[4] = _t; } \
    if (t8[3] < t8[2]) { _t = t8[2]; t8[2] = t8[3]; t8[3] = _t; } \
    if (t8[2] < t8[1]) { _t = t8[1]; t8[1] = t8[2]; t8[2] = _t; } \
    if (t8[1] < t8[0]) { _t = t8[0]; t8[0] = t8[1]; t8[1] = _t; } \
  } while (0)

// ---------------- Kernel 1: xx[row] = sum_d x^2 ----------------
__global__ __launch_bounds__(256) void k_xx(const float* __restrict__ x,
                                            float* __restrict__ xx) {
  int row  = blockIdx.x * 4 + (threadIdx.x >> 6);
  int lane = threadIdx.x & 63;
  float2 v = *reinterpret_cast<const float2*>(x + (size_t)row * DD + lane * 2);
  float p = v.x * v.x + v.y * v.y;
  #pragma unroll
  for (int off = 1; off < 64; off <<= 1) p += __shfl_xor(p, off);
  if (lane == 0) xx[row] = p;
}

// ---------------- Kernel 2: dual GEMM  s = x@Ws, y = x@Wn ----------------
__global__ __launch_bounds__(256) void k_gemm(const float* __restrict__ x,
                                              const float* __restrict__ Ws,
                                              const float* __restrict__ Wn,
                                              const float* __restrict__ bias,
                                              float* __restrict__ hbase,
                                              float* __restrict__ y) {
  __shared__ __align__(16) float xt[128 * 64];    // [k][r]
  __shared__ __align__(16) float wt[128 * 128];   // [k][c]
  int tid = threadIdx.x;
  size_t r0 = (size_t)blockIdx.x * 64;

  { // stage x transposed
    int rr = tid >> 2, kp = (tid & 3) << 5;
    const float* src = x + (r0 + rr) * DD + kp;
    #pragma unroll
    for (int q = 0; q < 8; ++q) {
      float4 v = *(const float4*)(src + (q << 2));
      int k = kp + (q << 2);
      xt[(k + 0) * 64 + rr] = v.x; xt[(k + 1) * 64 + rr] = v.y;
      xt[(k + 2) * 64 + rr] = v.z; xt[(k + 3) * 64 + rr] = v.w;
    }
  }
  { // stage Ws (row-major copy)
    const float4* s4 = (const float4*)Ws;
    float4* w4 = (float4*)wt;
    #pragma unroll
    for (int q = 0; q < 16; ++q) w4[q * 256 + tid] = s4[q * 256 + tid];
  }
  __syncthreads();

  int tc = tid & 15, tr = tid >> 4;
  float accS[4][8], accY[4][8];
  #pragma unroll
  for (int i = 0; i < 4; ++i)
    #pragma unroll
    for (int u = 0; u < 8; ++u) { accS[i][u] = 0.f; accY[i][u] = 0.f; }

  #pragma unroll 2
  for (int k = 0; k < 128; ++k) {
    float4 a4 = *(const float4*)(xt + k * 64 + (tr << 2));
    float4 w0 = *(const float4*)(wt + k * 128 + (tc << 2));
    float4 w1 = *(const float4*)(wt + k * 128 + 64 + (tc << 2));
    float aa[4] = {a4.x, a4.y, a4.z, a4.w};
    float ww[8] = {w0.x, w0.y, w0.z, w0.w, w1.x, w1.y, w1.z, w1.w};
    #pragma unroll
    for (int i = 0; i < 4; ++i)
      #pragma unroll
      for (int u = 0; u < 8; ++u) accS[i][u] = fmaf(aa[i], ww[u], accS[i][u]);
  }
  __syncthreads();
  { // stage Wn
    const float4* s4 = (const float4*)Wn;
    float4* w4 = (float4*)wt;
    #pragma unroll
    for (int q = 0; q < 16; ++q) w4[q * 256 + tid] = s4[q * 256 + tid];
  }
  __syncthreads();
  #pragma unroll 2
  for (int k = 0; k < 128; ++k) {
    float4 a4 = *(const float4*)(xt + k * 64 + (tr << 2));
    float4 w0 = *(const float4*)(wt + k * 128 + (tc << 2));
    float4 w1 = *(const float4*)(wt + k * 128 + 64 + (tc << 2));
    float aa[4] = {a4.x, a4.y, a4.z, a4.w};
    float ww[8] = {w0.x, w0.y, w0.z, w0.w, w1.x, w1.y, w1.z, w1.w};
    #pragma unroll
    for (int i = 0; i < 4; ++i)
      #pragma unroll
      for (int u = 0; u < 8; ++u) accY[i][u] = fmaf(aa[i], ww[u], accY[i][u]);
  }

  float4 bv0 = *(const float4*)(bias + (tc << 2));
  float4 bv1 = *(const float4*)(bias + 64 + (tc << 2));
  float bb[8] = {bv0.x, bv0.y, bv0.z, bv0.w, bv1.x, bv1.y, bv1.z, bv1.w};
  #pragma unroll
  for (int i = 0; i < 4; ++i) {
    size_t row = r0 + (tr << 2) + i;
    float h[8];
    #pragma unroll
    for (int u = 0; u < 8; ++u) h[u] = (accS[i][u] + accY[i][u]) + bb[u];
    *(float4*)(y + row * DD + (tc << 2))      = make_float4(accY[i][0], accY[i][1], accY[i][2], accY[i][3]);
    *(float4*)(y + row * DD + 64 + (tc << 2)) = make_float4(accY[i][4], accY[i][5], accY[i][6], accY[i][7]);
    *(float4*)(hbase + row * DD + (tc << 2))      = make_float4(h[0], h[1], h[2], h[3]);
    *(float4*)(hbase + row * DD + 64 + (tc << 2)) = make_float4(h[4], h[5], h[6], h[7]);
  }
}

// ---------------- Kernel 3: pairwise dist + 8-NN selection ----------------
// grid 256; XCD-swizzled: batch = blockIdx&7 (all 32 tiles of a batch share
// one XCD's L2). block 512 (8 waves). LDS ~66.6 KB -> 2 blocks/CU = 4 waves/SIMD.
// Bt[32][264] and Dd[64][132] UNION one buffer U; dist scanned in col-halves.
__global__ __launch_bounds__(512) void k_knn(const float* __restrict__ x,
                                             const float* __restrict__ xx,
                                             int* __restrict__ nbr) {
  __shared__ __align__(16) float At[128 * 64];   // [k][n]  32 KB
  __shared__ __align__(16) float U[64 * 132];    // 33 KB: Bt[32][264] | Dd[64][132] | merge
  __shared__ float xxn[64];
  __shared__ float xxm[256];

  int tid = threadIdx.x;
  int b  = blockIdx.x & 7;               // XCD-affine batch
  int n0 = (blockIdx.x >> 3) << 6;
  const float* xb  = x  + ((size_t)b << 11) * DD;
  const float* xxb = xx + ((size_t)b << 11);

  float* Bt = U;                         // stride 264, 32 rows
  float* Dd = U;                         // stride 132, 64 rows

  { // stage A transposed: lanes write consecutive columns (2-way banks, free)
    int rr = tid & 63, kp = (tid >> 6) << 4;
    const float* src = xb + (size_t)(n0 + rr) * DD + kp;
    #pragma unroll
    for (int q = 0; q < 4; ++q) {
      float4 v = *(const float4*)(src + (q << 2));
      int k = kp + (q << 2);
      At[(k + 0) * 64 + rr] = v.x; At[(k + 1) * 64 + rr] = v.y;
      At[(k + 2) * 64 + rr] = v.z; At[(k + 3) * 64 + rr] = v.w;
    }
  }
  if (tid < 64) xxn[tid] = xxb[n0 + tid];

  int tc = tid & 31, tr = tid >> 5;        // compute: rows tr*4+i, cols {tc*4+j, 128+tc*4+j}
  int srow = tid >> 3, sj = tid & 7;       // scan: 8 scanners/row, scalar stride-8
  int my_n = n0 + srow;
  int mrr = tid >> 1, kq = (tid & 1) << 4; // Bt staging: 2 threads/row, 16 k each

  ull t8[8];
  #pragma unroll
  for (int q = 0; q < 8; ++q) t8[q] = ~0ull;

  // prefetch (mt=0, kc=0)
  float4 bpre[4];
  {
    const float* bs = xb + (size_t)mrr * DD + kq;
    #pragma unroll
    for (int q = 0; q < 4; ++q) bpre[q] = *(const float4*)(bs + (q << 2));
  }
  float xmreg = (tid < 256) ? xxb[tid] : 0.f;

  for (int mt = 0; mt < 8; ++mt) {
    int m0 = mt << 8;

    float acc[4][8];
    #pragma unroll
    for (int i = 0; i < 4; ++i)
      #pragma unroll
      for (int u = 0; u < 8; ++u) acc[i][u] = 0.f;

    for (int kc = 0; kc < 4; ++kc) {
      __syncthreads();   // prev readers of U done (compute kc-1 / prev-mt scan h1)
      // write Bt chunk: lanes write consecutive columns -> 2-way, free
      #pragma unroll
      for (int q = 0; q < 4; ++q) {
        int k = kq + (q << 2);
        Bt[(k + 0) * 264 + mrr] = bpre[q].x; Bt[(k + 1) * 264 + mrr] = bpre[q].y;
        Bt[(k + 2) * 264 + mrr] = bpre[q].z; Bt[(k + 3) * 264 + mrr] = bpre[q].w;
      }
      if (kc == 0 && tid < 256) xxm[tid] = xmreg;
      // issue next-chunk global loads (complete during compute)
      if (!(mt == 7 && kc == 3)) {
        int nmt = (kc == 3) ? mt + 1 : mt;
        int nkc = (kc + 1) & 3;
        const float* ns = xb + (size_t)((nmt << 8) + mrr) * DD + (nkc << 5) + kq;
        #pragma unroll
        for (int q = 0; q < 4; ++q) bpre[q] = *(const float4*)(ns + (q << 2));
        if (kc == 3 && tid < 256) xmreg = xxb[(nmt << 8) + tid];
      }
      __syncthreads();   // Bt ready

      const float* Ab = At + ((kc << 5) * 64) + (tr << 2);
      const float* Bb = Bt + (tc << 2);
      #pragma unroll 4
      for (int k = 0; k < 32; ++k) {
        float4 a4 = *(const float4*)(Ab + k * 64);
        float4 b0 = *(const float4*)(Bb + k * 264);
        float4 b1 = *(const float4*)(Bb + k * 264 + 128);
        float aa[4]  = {a4.x, a4.y, a4.z, a4.w};
        float bbv[8] = {b0.x, b0.y, b0.z, b0.w, b1.x, b1.y, b1.z, b1.w};
        #pragma unroll
        for (int i = 0; i < 4; ++i)
          #pragma unroll
          for (int u = 0; u < 8; ++u) acc[i][u] = fmaf(aa[i], bbv[u], acc[i][u]);
      }
    }

    float4 xn4 = *(const float4*)(xxn + (tr << 2));
    float4 xm0 = *(const float4*)(xxm + (tc << 2));
    float4 xm1 = *(const float4*)(xxm + 128 + (tc << 2));
    float xnv[4] = {xn4.x, xn4.y, xn4.z, xn4.w};
    float xlo[4] = {xm0.x, xm0.y, xm0.z, xm0.w};
    float xhi[4] = {xm1.x, xm1.y, xm1.z, xm1.w};

    // ---- half 0: cols m0+0..127 ----
    __syncthreads();   // all waves done reading Bt(kc=3) before Dd overwrites U
    #pragma unroll
    for (int i = 0; i < 4; ++i) {
      float4 d0;
      d0.x = fmaxf((xnv[i] - 2.f * acc[i][0]) + xlo[0], 0.f);
      d0.y = fmaxf((xnv[i] - 2.f * acc[i][1]) + xlo[1], 0.f);
      d0.z = fmaxf((xnv[i] - 2.f * acc[i][2]) + xlo[2], 0.f);
      d0.w = fmaxf((xnv[i] - 2.f * acc[i][3]) + xlo[3], 0.f);
      *(float4*)(Dd + ((tr << 2) + i) * 132 + (tc << 2)) = d0;
    }
    __syncthreads();   // Dd half0 ready
    {
      const float* dbase = Dd + srow * 132 + sj;
      #pragma unroll 8
      for (int t = 0; t < 16; ++t) {
        float d = dbase[t << 3];
        int mg = m0 + sj + (t << 3);
        ull cand = (((ull)__float_as_uint(d)) << 32) | (unsigned)mg;
        if (mg != my_n && cand < t8[7]) INS8(t8, cand);
      }
    }
    // ---- half 1: cols m0+128..255 ----
    __syncthreads();   // scan half0 done
    #pragma unroll
    for (int i = 0; i < 4; ++i) {
      float4 d1;
      d1.x = fmaxf((xnv[i] - 2.f * acc[i][4]) + xhi[0], 0.f);
      d1.y = fmaxf((xnv[i] - 2.f * acc[i][5]) + xhi[1], 0.f);
      d1.z = fmaxf((xnv[i] - 2.f * acc[i][6]) + xhi[2], 0.f);
      d1.w = fmaxf((xnv[i] - 2.f * acc[i][7]) + xhi[3], 0.f);
      *(float4*)(Dd + ((tr << 2) + i) * 132 + (tc << 2)) = d1;
    }
    __syncthreads();   // Dd half1 ready
    {
      const float* dbase = Dd + srow * 132 + sj;
      #pragma unroll 8
      for (int t = 0; t < 16; ++t) {
        float d = dbase[t << 3];
        int mg = m0 + 128 + sj + (t << 3);
        ull cand = (((ull)__float_as_uint(d)) << 32) | (unsigned)mg;
        if (mg != my_n && cand < t8[7]) INS8(t8, cand);
      }
    }
    // loop-top barrier protects next Bt write vs this scan
  }

  __syncthreads();   // all scans done before merge buffer overwrites U
  ull* mbuf = (ull*)U;  // 64 rows * 8 lists * 8 u64 = 32 KB <= 33 KB
  #pragma unroll
  for (int q = 0; q < 8; ++q) mbuf[((srow << 3) + sj) * 8 + q] = t8[q];
  __syncthreads();
  if (sj == 0) {
    for (int j = 1; j < 8; ++j) {
      #pragma unroll
      for (int q = 0; q < 8; ++q) {
        ull cand = mbuf[((srow << 3) + j) * 8 + q];
        if (cand < t8[7]) INS8(t8, cand);
      }
    }
    int* op = nbr + (((size_t)b << 11) + my_n) * 8;
    #pragma unroll
    for (int q = 0; q < 8; ++q) op[q] = (int)(t8[q] & 0xffffffffu);
  }
}

// ---------------- Kernel 4: gather + KAN rational + BN partial sums ----------------
// grid 256 x 256thr; 64 rows/block; LDS half-reduce, then 256 f64 atomics/block.
__global__ __launch_bounds__(256) void k_kan(const float* __restrict__ hbase,
                                             const float* __restrict__ y,
                                             const int* __restrict__ nbr,
                                             const float* __restrict__ kan_a,
                                             const float* __restrict__ kan_b,
                                             float* __restrict__ hkan,
                                             double* __restrict__ sums) {
  __shared__ double redA[256], redB[256];
  int f = threadIdx.x & 127;
  int half = threadIdx.x >> 7;
  int r0 = blockIdx.x * 64 + half * 32;
  int bb = r0 >> 11;
  const float* yb = y + ((size_t)bb << 11) * DD;
  float a0 = kan_a[f * 3 + 0], a1 = kan_a[f * 3 + 1], a2 = kan_a[f * 3 + 2];
  float b0 = kan_b[f * 2 + 0], b1 = kan_b[f * 2 + 1];
  float disf = (float)(1.0 / sqrt((double)(8.0f + 1e-6f)));
  float cf = disf * disf;
  double sh = 0.0, sh2 = 0.0;
  for (int i = 0; i < 32; ++i) {
    int r = r0 + i;
    const int* np_ = nbr + (size_t)r * 8;
    float t = 0.f;
    #pragma unroll
    for (int j = 0; j < 8; ++j) {
      int m = np_[j];
      float yv = yb[(size_t)m * DD + f];
      t = fmaf(cf, yv, t);
    }
    float h = hbase[(size_t)r * DD + f] + t;
    float h2 = h * h;
    float num = (a0 + a1 * h) + a2 * h2;
    float den = 1.0f + fabsf(b0 * h + b1 * h2);
    float hk = num / (den + 1e-8f);
    hkan[(size_t)r * DD + f] = hk;
    sh += (double)hk; sh2 += (double)hk * (double)hk;
  }
  redA[threadIdx.x] = sh; redB[threadIdx.x] = sh2;
  __syncthreads();
  if (half == 0) {
    atomicAdd(&sums[f], sh + redA[f + 128]);
    atomicAdd(&sums[128 + f], sh2 + redB[f + 128]);
  }
}

// ---------------- Kernel 5: BN finalize + normalize ----------------
__global__ __launch_bounds__(256) void k_bn(const float* __restrict__ hkan,
                                            const double* __restrict__ sums,
                                            const float* __restrict__ gamma,
                                            const float* __restrict__ beta,
                                            float* __restrict__ out) {
  __shared__ float mn[128], sc[128], bt[128];
  int tid = threadIdx.x;
  if (tid < 128) {
    double M = (double)(BB * NN);
    double mean = sums[tid] / M;
    double var = sums[128 + tid] / M - mean * mean;
    if (var < 0.0) var = 0.0;
    mn[tid] = (float)mean;
    sc[tid] = (float)(1.0 / sqrt(var + 1e-5)) * gamma[tid];
    bt[tid] = beta[tid];
  }
  __syncthreads();
  const int total4 = BB * NN * DD / 4;
  for (int i4 = blockIdx.x * blockDim.x + threadIdx.x; i4 < total4;
       i4 += gridDim.x * blockDim.x) {
    float4 v = ((const float4*)hkan)[i4];
    int fb = (i4 * 4) & 127;
    float4 o;
    o.x = (v.x - mn[fb + 0]) * sc[fb + 0] + bt[fb + 0];
    o.y = (v.y - mn[fb + 1]) * sc[fb + 1] + bt[fb + 1];
    o.z = (v.z - mn[fb + 2]) * sc[fb + 2] + bt[fb + 2];
    o.w = (v.w - mn[fb + 3]) * sc[fb + 3] + bt[fb + 3];
    ((float4*)out)[i4] = o;
  }
}

extern "C" void kernel_launch(void* const* d_in, const int* in_sizes, int n_in,
                              void* d_out, int out_size, void* d_ws, size_t ws_size,
                              hipStream_t stream) {
  const float* x     = (const float*)d_in[0];
  const float* Ws    = (const float*)d_in[1];
  const float* Wn    = (const float*)d_in[2];
  const float* ka    = (const float*)d_in[3];
  const float* kb    = (const float*)d_in[4];
  const float* bias  = (const float*)d_in[5];
  const float* gamma = (const float*)d_in[6];
  const float* beta  = (const float*)d_in[7];
  float* out = (float*)d_out;

  char* ws = (char*)d_ws;
  float*  xx    = (float*)(ws + 0);          //  64 KB
  int*    nbr   = (int*)(ws + 65536);        // 512 KB
  double* sums  = (double*)(ws + 589824);    //   2 KB
  float*  y     = (float*)(ws + 1048576);    //   8 MB
  float*  hbase = (float*)(ws + 9437184);    //   8 MB
  float*  hkan  = (float*)(ws + 17825792);   //   8 MB

  hipMemsetAsync(sums, 0, 256 * sizeof(double), stream);
  k_xx  <<<4096, 256, 0, stream>>>(x, xx);
  k_gemm<<<256,  256, 0, stream>>>(x, Ws, Wn, bias, hbase, y);
  k_knn <<<256,  512, 0, stream>>>(x, xx, nbr);
  k_kan <<<256,  256, 0, stream>>>(hbase, y, nbr, ka, kb, hkan, sums);
  k_bn  <<<1024, 256, 0, stream>>>(hkan, sums, gamma, beta, out);
}

// Round 6
// 236.211 us; speedup vs baseline: 1.4770x; 1.0196x over previous
//
#include <hip/hip_runtime.h>
#include <stdint.h>

#define BB 8
#define NN 2048
#define DD 128

typedef unsigned long long ull;

// insertion into sorted-ascending 8-slot register array (static indices only)
#define INS8(t8, cand) do { \
    t8[7] = (cand); ull _t; \
    if (t8[7] < t8[6]) { _t = t8[6]; t8[6] = t8[7]; t8[7] = _t; } \
    if (t8[6] < t8[5]) { _t = t8[5]; t8[5] = t8[6]; t8[6] = _t; } \
    if (t8[5] < t8[4]) { _t = t8[4]; t8[4] = t8[5]; t8[5] = _t; } \
    if (t8[4] < t8[3]) { _t = t8[3]; t8[3] = t8[4]; t8[4] = _t; } \
    if (t8[3] < t8[2]) { _t = t8[2]; t8[2] = t8[3]; t8[3] = _t; } \
    if (t8[2] < t8[1]) { _t = t8[1]; t8[1] = t8[2]; t8[2] = _t; } \
    if (t8[1] < t8[0]) { _t = t8[0]; t8[0] = t8[1]; t8[1] = _t; } \
  } while (0)

// ---------------- Kernel 1: xx[row] = sum_d x^2 ----------------
__global__ __launch_bounds__(256) void k_xx(const float* __restrict__ x,
                                            float* __restrict__ xx) {
  int row  = blockIdx.x * 4 + (threadIdx.x >> 6);
  int lane = threadIdx.x & 63;
  float2 v = *reinterpret_cast<const float2*>(x + (size_t)row * DD + lane * 2);
  float p = v.x * v.x + v.y * v.y;
  #pragma unroll
  for (int off = 1; off < 64; off <<= 1) p += __shfl_xor(p, off);
  if (lane == 0) xx[row] = p;
}

// ---------------- Kernel 2: dual GEMM  s = x@Ws, y = x@Wn ----------------
__global__ __launch_bounds__(256) void k_gemm(const float* __restrict__ x,
                                              const float* __restrict__ Ws,
                                              const float* __restrict__ Wn,
                                              const float* __restrict__ bias,
                                              float* __restrict__ hbase,
                                              float* __restrict__ y) {
  __shared__ __align__(16) float xt[128 * 64];    // [k][r]
  __shared__ __align__(16) float wt[128 * 128];   // [k][c]
  int tid = threadIdx.x;
  size_t r0 = (size_t)blockIdx.x * 64;

  { // stage x transposed
    int rr = tid >> 2, kp = (tid & 3) << 5;
    const float* src = x + (r0 + rr) * DD + kp;
    #pragma unroll
    for (int q = 0; q < 8; ++q) {
      float4 v = *(const float4*)(src + (q << 2));
      int k = kp + (q << 2);
      xt[(k + 0) * 64 + rr] = v.x; xt[(k + 1) * 64 + rr] = v.y;
      xt[(k + 2) * 64 + rr] = v.z; xt[(k + 3) * 64 + rr] = v.w;
    }
  }
  { // stage Ws (row-major copy)
    const float4* s4 = (const float4*)Ws;
    float4* w4 = (float4*)wt;
    #pragma unroll
    for (int q = 0; q < 16; ++q) w4[q * 256 + tid] = s4[q * 256 + tid];
  }
  __syncthreads();

  int tc = tid & 15, tr = tid >> 4;
  float accS[4][8], accY[4][8];
  #pragma unroll
  for (int i = 0; i < 4; ++i)
    #pragma unroll
    for (int u = 0; u < 8; ++u) { accS[i][u] = 0.f; accY[i][u] = 0.f; }

  #pragma unroll 2
  for (int k = 0; k < 128; ++k) {
    float4 a4 = *(const float4*)(xt + k * 64 + (tr << 2));
    float4 w0 = *(const float4*)(wt + k * 128 + (tc << 2));
    float4 w1 = *(const float4*)(wt + k * 128 + 64 + (tc << 2));
    float aa[4] = {a4.x, a4.y, a4.z, a4.w};
    float ww[8] = {w0.x, w0.y, w0.z, w0.w, w1.x, w1.y, w1.z, w1.w};
    #pragma unroll
    for (int i = 0; i < 4; ++i)
      #pragma unroll
      for (int u = 0; u < 8; ++u) accS[i][u] = fmaf(aa[i], ww[u], accS[i][u]);
  }
  __syncthreads();
  { // stage Wn
    const float4* s4 = (const float4*)Wn;
    float4* w4 = (float4*)wt;
    #pragma unroll
    for (int q = 0; q < 16; ++q) w4[q * 256 + tid] = s4[q * 256 + tid];
  }
  __syncthreads();
  #pragma unroll 2
  for (int k = 0; k < 128; ++k) {
    float4 a4 = *(const float4*)(xt + k * 64 + (tr << 2));
    float4 w0 = *(const float4*)(wt + k * 128 + (tc << 2));
    float4 w1 = *(const float4*)(wt + k * 128 + 64 + (tc << 2));
    float aa[4] = {a4.x, a4.y, a4.z, a4.w};
    float ww[8] = {w0.x, w0.y, w0.z, w0.w, w1.x, w1.y, w1.z, w1.w};
    #pragma unroll
    for (int i = 0; i < 4; ++i)
      #pragma unroll
      for (int u = 0; u < 8; ++u) accY[i][u] = fmaf(aa[i], ww[u], accY[i][u]);
  }

  float4 bv0 = *(const float4*)(bias + (tc << 2));
  float4 bv1 = *(const float4*)(bias + 64 + (tc << 2));
  float bb[8] = {bv0.x, bv0.y, bv0.z, bv0.w, bv1.x, bv1.y, bv1.z, bv1.w};
  #pragma unroll
  for (int i = 0; i < 4; ++i) {
    size_t row = r0 + (tr << 2) + i;
    float h[8];
    #pragma unroll
    for (int u = 0; u < 8; ++u) h[u] = (accS[i][u] + accY[i][u]) + bb[u];
    *(float4*)(y + row * DD + (tc << 2))      = make_float4(accY[i][0], accY[i][1], accY[i][2], accY[i][3]);
    *(float4*)(y + row * DD + 64 + (tc << 2)) = make_float4(accY[i][4], accY[i][5], accY[i][6], accY[i][7]);
    *(float4*)(hbase + row * DD + (tc << 2))      = make_float4(h[0], h[1], h[2], h[3]);
    *(float4*)(hbase + row * DD + 64 + (tc << 2)) = make_float4(h[4], h[5], h[6], h[7]);
  }
}

// ---------------- Kernel 3: pairwise dist + 8-NN (half m-range per block) ----
// grid 512 = 8 batches (XCD-affine) x 32 n-tiles x 2 m-halves. block 512.
// LDS ~66.6 KB -> 2 blocks/CU resident = 4 waves/SIMD.
// Each block scans m in [half*1024, half*1024+1024) over 4 mt-tiles of 256;
// per-row top-8 (packed u64) written to cand[row][half][8]; k_mrg folds halves.
__global__ __launch_bounds__(512) void k_knn(const float* __restrict__ x,
                                             const float* __restrict__ xx,
                                             ull* __restrict__ cand) {
  __shared__ __align__(16) float At[128 * 64];   // [k][n]  32 KB
  __shared__ __align__(16) float U[64 * 132];    // 33 KB: Bt[32][264] | Dd[64][132] | merge
  __shared__ float xxn[64];
  __shared__ float xxm[256];

  int tid = threadIdx.x;
  int b    = blockIdx.x & 7;             // XCD-affine batch
  int rest = blockIdx.x >> 3;
  int n0   = (rest & 31) << 6;
  int half = rest >> 5;
  int mbase = half << 10;
  const float* xb  = x  + ((size_t)b << 11) * DD;
  const float* xxb = xx + ((size_t)b << 11);

  float* Bt = U;                         // stride 264, 32 rows
  float* Dd = U;                         // stride 132, 64 rows

  { // stage A transposed: lanes write consecutive columns (2-way banks, free)
    int rr = tid & 63, kp = (tid >> 6) << 4;
    const float* src = xb + (size_t)(n0 + rr) * DD + kp;
    #pragma unroll
    for (int q = 0; q < 4; ++q) {
      float4 v = *(const float4*)(src + (q << 2));
      int k = kp + (q << 2);
      At[(k + 0) * 64 + rr] = v.x; At[(k + 1) * 64 + rr] = v.y;
      At[(k + 2) * 64 + rr] = v.z; At[(k + 3) * 64 + rr] = v.w;
    }
  }
  if (tid < 64) xxn[tid] = xxb[n0 + tid];

  int tc = tid & 31, tr = tid >> 5;        // compute: rows tr*4+i, cols {tc*4+j, 128+tc*4+j}
  int srow = tid >> 3, sj = tid & 7;       // scan: 8 scanners/row, scalar stride-8
  int my_n = n0 + srow;
  int mrr = tid >> 1, kq = (tid & 1) << 4; // Bt staging: 2 threads/row, 16 k each

  ull t8[8];
  #pragma unroll
  for (int q = 0; q < 8; ++q) t8[q] = ~0ull;

  // prefetch (mt=0, kc=0)
  float4 bpre[4];
  {
    const float* bs = xb + (size_t)(mbase + mrr) * DD + kq;
    #pragma unroll
    for (int q = 0; q < 4; ++q) bpre[q] = *(const float4*)(bs + (q << 2));
  }
  float xmreg = (tid < 256) ? xxb[mbase + tid] : 0.f;

  for (int mt = 0; mt < 4; ++mt) {
    int m0 = mbase + (mt << 8);

    float acc[4][8];
    #pragma unroll
    for (int i = 0; i < 4; ++i)
      #pragma unroll
      for (int u = 0; u < 8; ++u) acc[i][u] = 0.f;

    for (int kc = 0; kc < 4; ++kc) {
      __syncthreads();   // prev readers of U done (compute kc-1 / prev-mt scan h1)
      // write Bt chunk: lanes write consecutive columns -> 2-way, free
      #pragma unroll
      for (int q = 0; q < 4; ++q) {
        int k = kq + (q << 2);
        Bt[(k + 0) * 264 + mrr] = bpre[q].x; Bt[(k + 1) * 264 + mrr] = bpre[q].y;
        Bt[(k + 2) * 264 + mrr] = bpre[q].z; Bt[(k + 3) * 264 + mrr] = bpre[q].w;
      }
      if (kc == 0 && tid < 256) xxm[tid] = xmreg;
      // issue next-chunk global loads (complete during compute)
      if (!(mt == 3 && kc == 3)) {
        int nmt = (kc == 3) ? mt + 1 : mt;
        int nkc = (kc + 1) & 3;
        const float* ns = xb + (size_t)(mbase + (nmt << 8) + mrr) * DD + (nkc << 5) + kq;
        #pragma unroll
        for (int q = 0; q < 4; ++q) bpre[q] = *(const float4*)(ns + (q << 2));
        if (kc == 3 && tid < 256) xmreg = xxb[mbase + (nmt << 8) + tid];
      }
      __syncthreads();   // Bt ready

      const float* Ab = At + ((kc << 5) * 64) + (tr << 2);
      const float* Bb = Bt + (tc << 2);
      #pragma unroll 4
      for (int k = 0; k < 32; ++k) {
        float4 a4 = *(const float4*)(Ab + k * 64);
        float4 b0 = *(const float4*)(Bb + k * 264);
        float4 b1 = *(const float4*)(Bb + k * 264 + 128);
        float aa[4]  = {a4.x, a4.y, a4.z, a4.w};
        float bbv[8] = {b0.x, b0.y, b0.z, b0.w, b1.x, b1.y, b1.z, b1.w};
        #pragma unroll
        for (int i = 0; i < 4; ++i)
          #pragma unroll
          for (int u = 0; u < 8; ++u) acc[i][u] = fmaf(aa[i], bbv[u], acc[i][u]);
      }
    }

    float4 xn4 = *(const float4*)(xxn + (tr << 2));
    float4 xm0 = *(const float4*)(xxm + (tc << 2));
    float4 xm1 = *(const float4*)(xxm + 128 + (tc << 2));
    float xnv[4] = {xn4.x, xn4.y, xn4.z, xn4.w};
    float xlo[4] = {xm0.x, xm0.y, xm0.z, xm0.w};
    float xhi[4] = {xm1.x, xm1.y, xm1.z, xm1.w};

    // ---- half 0 of tile: cols m0+0..127 ----
    __syncthreads();   // all waves done reading Bt(kc=3) before Dd overwrites U
    #pragma unroll
    for (int i = 0; i < 4; ++i) {
      float4 d0;
      d0.x = fmaxf((xnv[i] - 2.f * acc[i][0]) + xlo[0], 0.f);
      d0.y = fmaxf((xnv[i] - 2.f * acc[i][1]) + xlo[1], 0.f);
      d0.z = fmaxf((xnv[i] - 2.f * acc[i][2]) + xlo[2], 0.f);
      d0.w = fmaxf((xnv[i] - 2.f * acc[i][3]) + xlo[3], 0.f);
      *(float4*)(Dd + ((tr << 2) + i) * 132 + (tc << 2)) = d0;
    }
    __syncthreads();   // Dd half0 ready
    {
      const float* dbase = Dd + srow * 132 + sj;
      #pragma unroll 8
      for (int t = 0; t < 16; ++t) {
        float d = dbase[t << 3];
        int mg = m0 + sj + (t << 3);
        ull cd = (((ull)__float_as_uint(d)) << 32) | (unsigned)mg;
        if (mg != my_n && cd < t8[7]) INS8(t8, cd);
      }
    }
    // ---- half 1 of tile: cols m0+128..255 ----
    __syncthreads();   // scan half0 done
    #pragma unroll
    for (int i = 0; i < 4; ++i) {
      float4 d1;
      d1.x = fmaxf((xnv[i] - 2.f * acc[i][4]) + xhi[0], 0.f);
      d1.y = fmaxf((xnv[i] - 2.f * acc[i][5]) + xhi[1], 0.f);
      d1.z = fmaxf((xnv[i] - 2.f * acc[i][6]) + xhi[2], 0.f);
      d1.w = fmaxf((xnv[i] - 2.f * acc[i][7]) + xhi[3], 0.f);
      *(float4*)(Dd + ((tr << 2) + i) * 132 + (tc << 2)) = d1;
    }
    __syncthreads();   // Dd half1 ready
    {
      const float* dbase = Dd + srow * 132 + sj;
      #pragma unroll 8
      for (int t = 0; t < 16; ++t) {
        float d = dbase[t << 3];
        int mg = m0 + 128 + sj + (t << 3);
        ull cd = (((ull)__float_as_uint(d)) << 32) | (unsigned)mg;
        if (mg != my_n && cd < t8[7]) INS8(t8, cd);
      }
    }
    // loop-top barrier protects next Bt write vs this scan
  }

  __syncthreads();   // all scans done before merge buffer overwrites U
  ull* mbuf = (ull*)U;  // 64 rows * 8 lists * 8 u64 = 32 KB <= 33 KB
  #pragma unroll
  for (int q = 0; q < 8; ++q) mbuf[((srow << 3) + sj) * 8 + q] = t8[q];
  __syncthreads();
  if (sj == 0) {
    for (int j = 1; j < 8; ++j) {
      #pragma unroll
      for (int q = 0; q < 8; ++q) {
        ull cd = mbuf[((srow << 3) + j) * 8 + q];
        if (cd < t8[7]) INS8(t8, cd);
      }
    }
    ull* cp = cand + ((((size_t)b << 11) + my_n) << 4) + (half << 3);
    #pragma unroll
    for (int q = 0; q < 8; ++q) cp[q] = t8[q];
  }
}

// ---------------- Kernel 3b: merge the two half-range top-8 lists ----------
__global__ __launch_bounds__(256) void k_mrg(const ull* __restrict__ cand,
                                             int* __restrict__ nbr) {
  int r = blockIdx.x * 256 + threadIdx.x;
  const ull* c = cand + ((size_t)r << 4);
  ull t8[8];
  #pragma unroll
  for (int q = 0; q < 8; ++q) t8[q] = c[q];
  #pragma unroll
  for (int q = 8; q < 16; ++q) {
    ull cd = c[q];
    if (cd < t8[7]) INS8(t8, cd);
  }
  int* op = nbr + (size_t)r * 8;
  #pragma unroll
  for (int q = 0; q < 8; ++q) op[q] = (int)(t8[q] & 0xffffffffu);
}

// ---------------- Kernel 4: gather + KAN rational + BN partial sums ----------------
// grid 256 x 256thr; 64 rows/block; LDS half-reduce, then 256 f64 atomics/block.
__global__ __launch_bounds__(256) void k_kan(const float* __restrict__ hbase,
                                             const float* __restrict__ y,
                                             const int* __restrict__ nbr,
                                             const float* __restrict__ kan_a,
                                             const float* __restrict__ kan_b,
                                             float* __restrict__ hkan,
                                             double* __restrict__ sums) {
  __shared__ double redA[256], redB[256];
  int f = threadIdx.x & 127;
  int half = threadIdx.x >> 7;
  int r0 = blockIdx.x * 64 + half * 32;
  int bb = r0 >> 11;
  const float* yb = y + ((size_t)bb << 11) * DD;
  float a0 = kan_a[f * 3 + 0], a1 = kan_a[f * 3 + 1], a2 = kan_a[f * 3 + 2];
  float b0 = kan_b[f * 2 + 0], b1 = kan_b[f * 2 + 1];
  float disf = (float)(1.0 / sqrt((double)(8.0f + 1e-6f)));
  float cf = disf * disf;
  double sh = 0.0, sh2 = 0.0;
  for (int i = 0; i < 32; ++i) {
    int r = r0 + i;
    const int* np_ = nbr + (size_t)r * 8;
    float t = 0.f;
    #pragma unroll
    for (int j = 0; j < 8; ++j) {
      int m = np_[j];
      float yv = yb[(size_t)m * DD + f];
      t = fmaf(cf, yv, t);
    }
    float h = hbase[(size_t)r * DD + f] + t;
    float h2 = h * h;
    float num = (a0 + a1 * h) + a2 * h2;
    float den = 1.0f + fabsf(b0 * h + b1 * h2);
    float hk = num / (den + 1e-8f);
    hkan[(size_t)r * DD + f] = hk;
    sh += (double)hk; sh2 += (double)hk * (double)hk;
  }
  redA[threadIdx.x] = sh; redB[threadIdx.x] = sh2;
  __syncthreads();
  if (half == 0) {
    atomicAdd(&sums[f], sh + redA[f + 128]);
    atomicAdd(&sums[128 + f], sh2 + redB[f + 128]);
  }
}

// ---------------- Kernel 5: BN finalize + normalize ----------------
__global__ __launch_bounds__(256) void k_bn(const float* __restrict__ hkan,
                                            const double* __restrict__ sums,
                                            const float* __restrict__ gamma,
                                            const float* __restrict__ beta,
                                            float* __restrict__ out) {
  __shared__ float mn[128], sc[128], bt[128];
  int tid = threadIdx.x;
  if (tid < 128) {
    double M = (double)(BB * NN);
    double mean = sums[tid] / M;
    double var = sums[128 + tid] / M - mean * mean;
    if (var < 0.0) var = 0.0;
    mn[tid] = (float)mean;
    sc[tid] = (float)(1.0 / sqrt(var + 1e-5)) * gamma[tid];
    bt[tid] = beta[tid];
  }
  __syncthreads();
  const int total4 = BB * NN * DD / 4;
  for (int i4 = blockIdx.x * blockDim.x + threadIdx.x; i4 < total4;
       i4 += gridDim.x * blockDim.x) {
    float4 v = ((const float4*)hkan)[i4];
    int fb = (i4 * 4) & 127;
    float4 o;
    o.x = (v.x - mn[fb + 0]) * sc[fb + 0] + bt[fb + 0];
    o.y = (v.y - mn[fb + 1]) * sc[fb + 1] + bt[fb + 1];
    o.z = (v.z - mn[fb + 2]) * sc[fb + 2] + bt[fb + 2];
    o.w = (v.w - mn[fb + 3]) * sc[fb + 3] + bt[fb + 3];
    ((float4*)out)[i4] = o;
  }
}

extern "C" void kernel_launch(void* const* d_in, const int* in_sizes, int n_in,
                              void* d_out, int out_size, void* d_ws, size_t ws_size,
                              hipStream_t stream) {
  const float* x     = (const float*)d_in[0];
  const float* Ws    = (const float*)d_in[1];
  const float* Wn    = (const float*)d_in[2];
  const float* ka    = (const float*)d_in[3];
  const float* kb    = (const float*)d_in[4];
  const float* bias  = (const float*)d_in[5];
  const float* gamma = (const float*)d_in[6];
  const float* beta  = (const float*)d_in[7];
  float* out = (float*)d_out;

  char* ws = (char*)d_ws;
  float*  xx    = (float*)(ws + 0);          //  64 KB
  int*    nbr   = (int*)(ws + 65536);        // 512 KB
  double* sums  = (double*)(ws + 589824);    //   2 KB
  float*  y     = (float*)(ws + 1048576);    //   8 MB
  float*  hbase = (float*)(ws + 9437184);    //   8 MB
  float*  hkan  = (float*)(ws + 17825792);   //   8 MB
  ull*    cand  = (ull*)(ws + 17825792);     //   2 MB (aliases hkan: dead before k_kan)

  hipMemsetAsync(sums, 0, 256 * sizeof(double), stream);
  k_xx  <<<4096, 256, 0, stream>>>(x, xx);
  k_gemm<<<256,  256, 0, stream>>>(x, Ws, Wn, bias, hbase, y);
  k_knn <<<512,  512, 0, stream>>>(x, xx, cand);
  k_mrg <<<64,   256, 0, stream>>>(cand, nbr);
  k_kan <<<256,  256, 0, stream>>>(hbase, y, nbr, ka, kb, hkan, sums);
  k_bn  <<<1024, 256, 0, stream>>>(hkan, sums, gamma, beta, out);
}

// Round 8
// 233.927 us; speedup vs baseline: 1.4914x; 1.0098x over previous
//
#include <hip/hip_runtime.h>
#include <stdint.h>

#define BB 8
#define NN 2048
#define DD 128

typedef unsigned long long ull;
typedef unsigned short u16;
typedef __attribute__((ext_vector_type(8))) short bf16x8;
typedef __attribute__((ext_vector_type(4))) float f32x4;

// insertion into sorted-ascending 8-slot register array (static indices only)
#define INS8(t8, cand) do { \
    t8[7] = (cand); ull _t; \
    if (t8[7] < t8[6]) { _t = t8[6]; t8[6] = t8[7]; t8[7] = _t; } \
    if (t8[6] < t8[5]) { _t = t8[5]; t8[5] = t8[6]; t8[6] = _t; } \
    if (t8[5] < t8[4]) { _t = t8[4]; t8[4] = t8[5]; t8[5] = _t; } \
    if (t8[4] < t8[3]) { _t = t8[3]; t8[3] = t8[4]; t8[4] = _t; } \
    if (t8[3] < t8[2]) { _t = t8[2]; t8[2] = t8[3]; t8[3] = _t; } \
    if (t8[2] < t8[1]) { _t = t8[1]; t8[1] = t8[2]; t8[2] = _t; } \
    if (t8[1] < t8[0]) { _t = t8[0]; t8[0] = t8[1]; t8[1] = _t; } \
  } while (0)

// ---------------- Kernel 0: split x into bf16 hi/lo ----------------
__device__ inline u16 f2bf_rn(float f) {
  uint32_t u = __float_as_uint(f);
  return (u16)((u + 0x7fffu + ((u >> 16) & 1u)) >> 16);
}
__global__ __launch_bounds__(256) void k_cvt(const float* __restrict__ x,
                                             u16* __restrict__ xh,
                                             u16* __restrict__ xl) {
  int i = (blockIdx.x * 256 + threadIdx.x) * 8;
  float4 v0 = *(const float4*)(x + i);
  float4 v1 = *(const float4*)(x + i + 4);
  float vv[8] = {v0.x, v0.y, v0.z, v0.w, v1.x, v1.y, v1.z, v1.w};
  bf16x8 hv, lv;
  #pragma unroll
  for (int j = 0; j < 8; ++j) {
    u16 h = f2bf_rn(vv[j]);
    float hf = __uint_as_float(((uint32_t)h) << 16);
    u16 l = f2bf_rn(vv[j] - hf);
    hv[j] = (short)h; lv[j] = (short)l;
  }
  *(bf16x8*)(xh + i) = hv;
  *(bf16x8*)(xl + i) = lv;
}

// ---------------- Kernel 1: xx[row] = sum_d x^2 ----------------
__global__ __launch_bounds__(256) void k_xx(const float* __restrict__ x,
                                            float* __restrict__ xx) {
  int row  = blockIdx.x * 4 + (threadIdx.x >> 6);
  int lane = threadIdx.x & 63;
  float2 v = *reinterpret_cast<const float2*>(x + (size_t)row * DD + lane * 2);
  float p = v.x * v.x + v.y * v.y;
  #pragma unroll
  for (int off = 1; off < 64; off <<= 1) p += __shfl_xor(p, off);
  if (lane == 0) xx[row] = p;
}

// ---------------- Kernel 2: dual GEMM  s = x@Ws, y = x@Wn ----------------
__global__ __launch_bounds__(256) void k_gemm(const float* __restrict__ x,
                                              const float* __restrict__ Ws,
                                              const float* __restrict__ Wn,
                                              const float* __restrict__ bias,
                                              float* __restrict__ hbase,
                                              float* __restrict__ y) {
  __shared__ __align__(16) float xt[128 * 64];    // [k][r]
  __shared__ __align__(16) float wt[128 * 128];   // [k][c]
  int tid = threadIdx.x;
  size_t r0 = (size_t)blockIdx.x * 64;

  { // stage x transposed
    int rr = tid >> 2, kp = (tid & 3) << 5;
    const float* src = x + (r0 + rr) * DD + kp;
    #pragma unroll
    for (int q = 0; q < 8; ++q) {
      float4 v = *(const float4*)(src + (q << 2));
      int k = kp + (q << 2);
      xt[(k + 0) * 64 + rr] = v.x; xt[(k + 1) * 64 + rr] = v.y;
      xt[(k + 2) * 64 + rr] = v.z; xt[(k + 3) * 64 + rr] = v.w;
    }
  }
  { // stage Ws (row-major copy)
    const float4* s4 = (const float4*)Ws;
    float4* w4 = (float4*)wt;
    #pragma unroll
    for (int q = 0; q < 16; ++q) w4[q * 256 + tid] = s4[q * 256 + tid];
  }
  __syncthreads();

  int tc = tid & 15, tr = tid >> 4;
  float accS[4][8], accY[4][8];
  #pragma unroll
  for (int i = 0; i < 4; ++i)
    #pragma unroll
    for (int u = 0; u < 8; ++u) { accS[i][u] = 0.f; accY[i][u] = 0.f; }

  #pragma unroll 2
  for (int k = 0; k < 128; ++k) {
    float4 a4 = *(const float4*)(xt + k * 64 + (tr << 2));
    float4 w0 = *(const float4*)(wt + k * 128 + (tc << 2));
    float4 w1 = *(const float4*)(wt + k * 128 + 64 + (tc << 2));
    float aa[4] = {a4.x, a4.y, a4.z, a4.w};
    float ww[8] = {w0.x, w0.y, w0.z, w0.w, w1.x, w1.y, w1.z, w1.w};
    #pragma unroll
    for (int i = 0; i < 4; ++i)
      #pragma unroll
      for (int u = 0; u < 8; ++u) accS[i][u] = fmaf(aa[i], ww[u], accS[i][u]);
  }
  __syncthreads();
  { // stage Wn
    const float4* s4 = (const float4*)Wn;
    float4* w4 = (float4*)wt;
    #pragma unroll
    for (int q = 0; q < 16; ++q) w4[q * 256 + tid] = s4[q * 256 + tid];
  }
  __syncthreads();
  #pragma unroll 2
  for (int k = 0; k < 128; ++k) {
    float4 a4 = *(const float4*)(xt + k * 64 + (tr << 2));
    float4 w0 = *(const float4*)(wt + k * 128 + (tc << 2));
    float4 w1 = *(const float4*)(wt + k * 128 + 64 + (tc << 2));
    float aa[4] = {a4.x, a4.y, a4.z, a4.w};
    float ww[8] = {w0.x, w0.y, w0.z, w0.w, w1.x, w1.y, w1.z, w1.w};
    #pragma unroll
    for (int i = 0; i < 4; ++i)
      #pragma unroll
      for (int u = 0; u < 8; ++u) accY[i][u] = fmaf(aa[i], ww[u], accY[i][u]);
  }

  float4 bv0 = *(const float4*)(bias + (tc << 2));
  float4 bv1 = *(const float4*)(bias + 64 + (tc << 2));
  float bb[8] = {bv0.x, bv0.y, bv0.z, bv0.w, bv1.x, bv1.y, bv1.z, bv1.w};
  #pragma unroll
  for (int i = 0; i < 4; ++i) {
    size_t row = r0 + (tr << 2) + i;
    float h[8];
    #pragma unroll
    for (int u = 0; u < 8; ++u) h[u] = (accS[i][u] + accY[i][u]) + bb[u];
    *(float4*)(y + row * DD + (tc << 2))      = make_float4(accY[i][0], accY[i][1], accY[i][2], accY[i][3]);
    *(float4*)(y + row * DD + 64 + (tc << 2)) = make_float4(accY[i][4], accY[i][5], accY[i][6], accY[i][7]);
    *(float4*)(hbase + row * DD + (tc << 2))      = make_float4(h[0], h[1], h[2], h[3]);
    *(float4*)(hbase + row * DD + 64 + (tc << 2)) = make_float4(h[4], h[5], h[6], h[7]);
  }
}

// ---------------- Kernel 3: MFMA pairwise dist SCREEN (approx top-8/split) ----
// grid 1024 = 8 batches (XCD-affine) x 32 n-groups(64) x 4 m-splits(512).
// block 256 = 4 waves; 3-term bf16 split dot (~1e-4 abs err on dist);
// candidates rescored exactly by k_rsc.
#define STAGE_LOAD(MC) do { \
    _Pragma("unroll") \
    for (int q = 0; q < 4; ++q) { \
      int ks_ = ((q & 1) << 2) + sks; \
      int mrow_ = mbase + ((MC) << 5) + ((q >> 1) << 4) + sr; \
      const u16* src_ = (ks_ < 4 ? xhb : xlb) + ((size_t)mrow_ << 7) + ((ks_ & 3) << 5) + (sg << 3); \
      bpre[q] = *(const float4*)src_; \
    } } while (0)

#define STAGE_WRITE(BUF) do { \
    _Pragma("unroll") \
    for (int q = 0; q < 4; ++q) \
      *(float4*)((char*)(&Bc[(BUF)][0]) + (((q << 8) + tid) << 4)) = bpre[q]; \
    } while (0)

__global__ __launch_bounds__(256, 4) void k_knn(const u16* __restrict__ xh,
                                                const u16* __restrict__ xl,
                                                const float* __restrict__ xx,
                                                ull* __restrict__ cand) {
  __shared__ __align__(16) u16 Bc[2][8192];   // 2 x 16 KB chunk buffers
  __shared__ float xxm[512];

  int tid = threadIdx.x;
  int lane = tid & 63, w = tid >> 6;
  int b = blockIdx.x & 7;                    // XCD-affine batch
  int rest = blockIdx.x >> 3;
  int n0 = (rest & 31) << 6;
  int msplit = rest >> 5;
  int mbase = msplit << 9;
  const u16*  xhb = xh + (((size_t)b << 11) << 7);
  const u16*  xlb = xl + (((size_t)b << 11) << 7);
  const float* xxb = xx + ((size_t)b << 11);

  { // stage xx for this m-range
    float2 t = *(const float2*)(xxb + mbase + tid * 2);
    xxm[tid * 2] = t.x; xxm[tid * 2 + 1] = t.y;
  }

  int r = lane & 15, g = lane >> 4;
  int myn = n0 + (w << 4) + r;
  float xxn = xxb[myn];

  // A-side (n) frags hoisted: ah = xh rows, al = xl rows
  bf16x8 ah[4], al[4];
  #pragma unroll
  for (int ks = 0; ks < 4; ++ks) {
    ah[ks] = *(const bf16x8*)(xhb + ((size_t)myn << 7) + (ks << 5) + (g << 3));
    al[ks] = *(const bf16x8*)(xlb + ((size_t)myn << 7) + (ks << 5) + (g << 3));
  }

  // staging decode
  int sr = tid & 15;          // row within panel
  int sg = (tid >> 4) & 3;    // k-slot group
  int sks = (tid >> 6) & 3;   // kstep within half

  ull t8[8];
  #pragma unroll
  for (int q = 0; q < 8; ++q) t8[q] = ~0ull;

  float4 bpre[4];
  STAGE_LOAD(0);
  STAGE_WRITE(0);
  STAGE_LOAD(1);
  __syncthreads();

  int cur = 0;
  for (int mc = 0; mc < 16; ++mc) {
    if (mc < 15) {
      STAGE_WRITE(cur ^ 1);              // chunk mc+1 -> other buffer
      if (mc < 14) STAGE_LOAD(mc + 2);   // prefetch chunk mc+2 to regs
    }
    const u16* Bcur = &Bc[cur][0];
    #pragma unroll
    for (int p = 0; p < 2; ++p) {
      bf16x8 bl[4];
      #pragma unroll
      for (int ks = 0; ks < 4; ++ks)
        bl[ks] = *(const bf16x8*)(Bcur + (((p << 3) + ks) << 9) + (lane << 3));
      f32x4 acc = {0.f, 0.f, 0.f, 0.f};
      #pragma unroll
      for (int i = 0; i < 4; ++i)
        acc = __builtin_amdgcn_mfma_f32_16x16x32_bf16(bl[i], ah[i], acc, 0, 0, 0);
      #pragma unroll
      for (int i = 0; i < 4; ++i) {
        bf16x8 bx = *(const bf16x8*)(Bcur + (((p << 3) + 4 + i) << 9) + (lane << 3));
        acc = __builtin_amdgcn_mfma_f32_16x16x32_bf16(bx, ah[i], acc, 0, 0, 0);
      }
      #pragma unroll
      for (int i = 0; i < 4; ++i)
        acc = __builtin_amdgcn_mfma_f32_16x16x32_bf16(bl[i], al[i], acc, 0, 0, 0);

      float4 xm4 = *(const float4*)(xxm + (mc << 5) + (p << 4) + (g << 2));
      float xmv[4] = {xm4.x, xm4.y, xm4.z, xm4.w};
      int mb0 = mbase + (mc << 5) + (p << 4) + (g << 2);
      #pragma unroll
      for (int e = 0; e < 4; ++e) {
        float d = fmaxf((xxn - 2.f * acc[e]) + xmv[e], 0.f);
        int m = mb0 + e;
        ull cd = (((ull)__float_as_uint(d)) << 32) | (unsigned)m;
        if (m != myn && cd < t8[7]) INS8(t8, cd);
      }
    }
    __syncthreads();
    cur ^= 1;
  }

  // merge the 4 g-lanes of each n
  ull* mbuf = (ull*)(&Bc[0][0]);   // 4 waves * 16 n * 4 g * 8 = 16 KB
  #pragma unroll
  for (int q = 0; q < 8; ++q)
    mbuf[(((((w << 4) + r) << 2) + g) << 3) + q] = t8[q];
  __syncthreads();
  if (g == 0) {
    for (int j = 1; j < 4; ++j) {
      #pragma unroll
      for (int q = 0; q < 8; ++q) {
        ull cd = mbuf[(((((w << 4) + r) << 2) + j) << 3) + q];
        if (cd < t8[7]) INS8(t8, cd);
      }
    }
    ull* cp = cand + ((((size_t)b << 11) + myn) << 5) + (msplit << 3);
    #pragma unroll
    for (int q = 0; q < 8; ++q) cp[q] = t8[q];
  }
}

// ---------------- Kernel 3b: EXACT f32 rescore of the 32 candidates/row ----
// 32 threads per row; dot via sequential fmaf chain (same arithmetic as the
// f32 path that passed rounds 1-6); per-row top-8 via LDS merge.
__global__ __launch_bounds__(256) void k_rsc(const float* __restrict__ x,
                                             const float* __restrict__ xx,
                                             const ull* __restrict__ cand,
                                             int* __restrict__ nbr) {
  __shared__ ull ex[256];
  int tid = threadIdx.x;
  int rloc = tid >> 5;               // 8 rows per block
  int c = tid & 31;
  int row = blockIdx.x * 8 + rloc;
  int b = row >> 11;
  ull cd = cand[((size_t)row << 5) + c];
  int m = (int)(cd & 0xffffffffu);
  const float* xn = x + (size_t)row * DD;
  const float* xm = x + ((size_t)(b << 11) + m) * DD;
  float acc = 0.f;
  #pragma unroll
  for (int d4 = 0; d4 < 32; ++d4) {
    float4 a = *(const float4*)(xn + (d4 << 2));
    float4 v = *(const float4*)(xm + (d4 << 2));
    acc = fmaf(a.x, v.x, acc);
    acc = fmaf(a.y, v.y, acc);
    acc = fmaf(a.z, v.z, acc);
    acc = fmaf(a.w, v.w, acc);
  }
  float dist = fmaxf((xx[row] - 2.f * acc) + xx[(b << 11) + m], 0.f);
  ex[tid] = (((ull)__float_as_uint(dist)) << 32) | (unsigned)m;
  __syncthreads();
  if (c == 0) {
    ull t8[8];
    #pragma unroll
    for (int q = 0; q < 8; ++q) t8[q] = ~0ull;
    #pragma unroll
    for (int q = 0; q < 32; ++q) {
      ull v = ex[(rloc << 5) + q];
      if (v < t8[7]) INS8(t8, v);
    }
    int* op = nbr + (size_t)row * 8;
    #pragma unroll
    for (int q = 0; q < 8; ++q) op[q] = (int)(t8[q] & 0xffffffffu);
  }
}

// ---------------- Kernel 4: gather + KAN rational + BN partial sums ----------------
__global__ __launch_bounds__(256) void k_kan(const float* __restrict__ hbase,
                                             const float* __restrict__ y,
                                             const int* __restrict__ nbr,
                                             const float* __restrict__ kan_a,
                                             const float* __restrict__ kan_b,
                                             float* __restrict__ hkan,
                                             double* __restrict__ sums) {
  __shared__ double redA[256], redB[256];
  int f = threadIdx.x & 127;
  int half = threadIdx.x >> 7;
  int r0 = blockIdx.x * 64 + half * 32;
  int bb = r0 >> 11;
  const float* yb = y + ((size_t)bb << 11) * DD;
  float a0 = kan_a[f * 3 + 0], a1 = kan_a[f * 3 + 1], a2 = kan_a[f * 3 + 2];
  float b0 = kan_b[f * 2 + 0], b1 = kan_b[f * 2 + 1];
  float disf = (float)(1.0 / sqrt((double)(8.0f + 1e-6f)));
  float cf = disf * disf;
  double sh = 0.0, sh2 = 0.0;
  for (int i = 0; i < 32; ++i) {
    int r = r0 + i;
    const int* np_ = nbr + (size_t)r * 8;
    float t = 0.f;
    #pragma unroll
    for (int j = 0; j < 8; ++j) {
      int m = np_[j];
      float yv = yb[(size_t)m * DD + f];
      t = fmaf(cf, yv, t);
    }
    float h = hbase[(size_t)r * DD + f] + t;
    float h2 = h * h;
    float num = (a0 + a1 * h) + a2 * h2;
    float den = 1.0f + fabsf(b0 * h + b1 * h2);
    float hk = num / (den + 1e-8f);
    hkan[(size_t)r * DD + f] = hk;
    sh += (double)hk; sh2 += (double)hk * (double)hk;
  }
  redA[threadIdx.x] = sh; redB[threadIdx.x] = sh2;
  __syncthreads();
  if (half == 0) {
    atomicAdd(&sums[f], sh + redA[f + 128]);
    atomicAdd(&sums[128 + f], sh2 + redB[f + 128]);
  }
}

// ---------------- Kernel 5: BN finalize + normalize ----------------
__global__ __launch_bounds__(256) void k_bn(const float* __restrict__ hkan,
                                            const double* __restrict__ sums,
                                            const float* __restrict__ gamma,
                                            const float* __restrict__ beta,
                                            float* __restrict__ out) {
  __shared__ float mn[128], sc[128], bt[128];
  int tid = threadIdx.x;
  if (tid < 128) {
    double M = (double)(BB * NN);
    double mean = sums[tid] / M;
    double var = sums[128 + tid] / M - mean * mean;
    if (var < 0.0) var = 0.0;
    mn[tid] = (float)mean;
    sc[tid] = (float)(1.0 / sqrt(var + 1e-5)) * gamma[tid];
    bt[tid] = beta[tid];
  }
  __syncthreads();
  const int total4 = BB * NN * DD / 4;
  for (int i4 = blockIdx.x * blockDim.x + threadIdx.x; i4 < total4;
       i4 += gridDim.x * blockDim.x) {
    float4 v = ((const float4*)hkan)[i4];
    int fb = (i4 * 4) & 127;
    float4 o;
    o.x = (v.x - mn[fb + 0]) * sc[fb + 0] + bt[fb + 0];
    o.y = (v.y - mn[fb + 1]) * sc[fb + 1] + bt[fb + 1];
    o.z = (v.z - mn[fb + 2]) * sc[fb + 2] + bt[fb + 2];
    o.w = (v.w - mn[fb + 3]) * sc[fb + 3] + bt[fb + 3];
    ((float4*)out)[i4] = o;
  }
}

extern "C" void kernel_launch(void* const* d_in, const int* in_sizes, int n_in,
                              void* d_out, int out_size, void* d_ws, size_t ws_size,
                              hipStream_t stream) {
  const float* x     = (const float*)d_in[0];
  const float* Ws    = (const float*)d_in[1];
  const float* Wn    = (const float*)d_in[2];
  const float* ka    = (const float*)d_in[3];
  const float* kb    = (const float*)d_in[4];
  const float* bias  = (const float*)d_in[5];
  const float* gamma = (const float*)d_in[6];
  const float* beta  = (const float*)d_in[7];
  float* out = (float*)d_out;

  char* ws = (char*)d_ws;
  float*  xx    = (float*)(ws + 0);          //  64 KB
  int*    nbr   = (int*)(ws + 65536);        // 512 KB
  double* sums  = (double*)(ws + 589824);    //   2 KB
  float*  y     = (float*)(ws + 1048576);    //   8 MB
  float*  hbase = (float*)(ws + 9437184);    //   8 MB
  float*  hkan  = (float*)(ws + 17825792);   //   8 MB (aliased below until k_kan)
  ull*    cand  = (ull*)(ws + 17825792);     //   4 MB (dead before k_kan writes hkan)
  u16*    xh    = (u16*)(ws + 22020096);     //   4 MB (dead before k_kan writes hkan)
  u16*    xl    = (u16*)d_out;               //   4 MB scratch in d_out; k_bn overwrites all of d_out last

  hipMemsetAsync(sums, 0, 256 * sizeof(double), stream);
  k_cvt <<<1024, 256, 0, stream>>>(x, xh, xl);
  k_xx  <<<4096, 256, 0, stream>>>(x, xx);
  k_gemm<<<256,  256, 0, stream>>>(x, Ws, Wn, bias, hbase, y);
  k_knn <<<1024, 256, 0, stream>>>(xh, xl, xx, cand);
  k_rsc <<<2048, 256, 0, stream>>>(x, xx, cand, nbr);
  k_kan <<<256,  256, 0, stream>>>(hbase, y, nbr, ka, kb, hkan, sums);
  k_bn  <<<1024, 256, 0, stream>>>(hkan, sums, gamma, beta, out);
}

// Round 9
// 204.365 us; speedup vs baseline: 1.7072x; 1.1447x over previous
//
#include <hip/hip_runtime.h>
#include <stdint.h>

#define BB 8
#define NN 2048
#define DD 128

typedef unsigned long long ull;
typedef unsigned short u16;
typedef __attribute__((ext_vector_type(8))) short bf16x8;
typedef __attribute__((ext_vector_type(4))) float f32x4;

// insertion into sorted-ascending 8-slot register array (static indices only)
#define INS8(t8, cand) do { \
    t8[7] = (cand); ull _t; \
    if (t8[7] < t8[6]) { _t = t8[6]; t8[6] = t8[7]; t8[7] = _t; } \
    if (t8[6] < t8[5]) { _t = t8[5]; t8[5] = t8[6]; t8[6] = _t; } \
    if (t8[5] < t8[4]) { _t = t8[4]; t8[4] = t8[5]; t8[5] = _t; } \
    if (t8[4] < t8[3]) { _t = t8[3]; t8[3] = t8[4]; t8[4] = _t; } \
    if (t8[3] < t8[2]) { _t = t8[2]; t8[2] = t8[3]; t8[3] = _t; } \
    if (t8[2] < t8[1]) { _t = t8[1]; t8[1] = t8[2]; t8[2] = _t; } \
    if (t8[1] < t8[0]) { _t = t8[0]; t8[0] = t8[1]; t8[1] = _t; } \
  } while (0)

__device__ inline u16 f2bf_rn(float f) {
  uint32_t u = __float_as_uint(f);
  return (u16)((u + 0x7fffu + ((u >> 16) & 1u)) >> 16);
}

typedef __attribute__((address_space(1))) const void gvoid_t;
typedef __attribute__((address_space(3))) void lvoid_t;
__device__ __forceinline__ void gload16(const void* g, void* l) {
  __builtin_amdgcn_global_load_lds((gvoid_t*)g, (lvoid_t*)l, 16, 0, 0);
}

// ---------------- Kernel 1: fused  xx[row] = sum x^2  +  bf16 hi/lo split ----
__global__ __launch_bounds__(256) void k_cvx(const float* __restrict__ x,
                                             float* __restrict__ xx,
                                             u16* __restrict__ xh,
                                             u16* __restrict__ xl) {
  int row  = blockIdx.x * 4 + (threadIdx.x >> 6);
  int lane = threadIdx.x & 63;
  float2 v = *reinterpret_cast<const float2*>(x + (size_t)row * DD + lane * 2);
  float p = v.x * v.x + v.y * v.y;
  #pragma unroll
  for (int off = 1; off < 64; off <<= 1) p += __shfl_xor(p, off);
  if (lane == 0) xx[row] = p;
  // bf16 hi/lo split of the two elements
  u16 h0 = f2bf_rn(v.x);
  u16 l0 = f2bf_rn(v.x - __uint_as_float(((uint32_t)h0) << 16));
  u16 h1 = f2bf_rn(v.y);
  u16 l1 = f2bf_rn(v.y - __uint_as_float(((uint32_t)h1) << 16));
  size_t o = (size_t)row * DD + lane * 2;
  *(uint32_t*)(xh + o) = (uint32_t)h0 | ((uint32_t)h1 << 16);
  *(uint32_t*)(xl + o) = (uint32_t)l0 | ((uint32_t)l1 << 16);
}

// ---------------- Kernel 2: dual GEMM  s = x@Ws, y = x@Wn ----------------
__global__ __launch_bounds__(256) void k_gemm(const float* __restrict__ x,
                                              const float* __restrict__ Ws,
                                              const float* __restrict__ Wn,
                                              const float* __restrict__ bias,
                                              float* __restrict__ hbase,
                                              float* __restrict__ y) {
  __shared__ __align__(16) float xt[128 * 64];    // [k][r]
  __shared__ __align__(16) float wt[128 * 128];   // [k][c]
  int tid = threadIdx.x;
  size_t r0 = (size_t)blockIdx.x * 64;

  { // stage x transposed
    int rr = tid >> 2, kp = (tid & 3) << 5;
    const float* src = x + (r0 + rr) * DD + kp;
    #pragma unroll
    for (int q = 0; q < 8; ++q) {
      float4 v = *(const float4*)(src + (q << 2));
      int k = kp + (q << 2);
      xt[(k + 0) * 64 + rr] = v.x; xt[(k + 1) * 64 + rr] = v.y;
      xt[(k + 2) * 64 + rr] = v.z; xt[(k + 3) * 64 + rr] = v.w;
    }
  }
  { // stage Ws (row-major copy)
    const float4* s4 = (const float4*)Ws;
    float4* w4 = (float4*)wt;
    #pragma unroll
    for (int q = 0; q < 16; ++q) w4[q * 256 + tid] = s4[q * 256 + tid];
  }
  __syncthreads();

  int tc = tid & 15, tr = tid >> 4;
  float accS[4][8], accY[4][8];
  #pragma unroll
  for (int i = 0; i < 4; ++i)
    #pragma unroll
    for (int u = 0; u < 8; ++u) { accS[i][u] = 0.f; accY[i][u] = 0.f; }

  #pragma unroll 2
  for (int k = 0; k < 128; ++k) {
    float4 a4 = *(const float4*)(xt + k * 64 + (tr << 2));
    float4 w0 = *(const float4*)(wt + k * 128 + (tc << 2));
    float4 w1 = *(const float4*)(wt + k * 128 + 64 + (tc << 2));
    float aa[4] = {a4.x, a4.y, a4.z, a4.w};
    float ww[8] = {w0.x, w0.y, w0.z, w0.w, w1.x, w1.y, w1.z, w1.w};
    #pragma unroll
    for (int i = 0; i < 4; ++i)
      #pragma unroll
      for (int u = 0; u < 8; ++u) accS[i][u] = fmaf(aa[i], ww[u], accS[i][u]);
  }
  __syncthreads();
  { // stage Wn
    const float4* s4 = (const float4*)Wn;
    float4* w4 = (float4*)wt;
    #pragma unroll
    for (int q = 0; q < 16; ++q) w4[q * 256 + tid] = s4[q * 256 + tid];
  }
  __syncthreads();
  #pragma unroll 2
  for (int k = 0; k < 128; ++k) {
    float4 a4 = *(const float4*)(xt + k * 64 + (tr << 2));
    float4 w0 = *(const float4*)(wt + k * 128 + (tc << 2));
    float4 w1 = *(const float4*)(wt + k * 128 + 64 + (tc << 2));
    float aa[4] = {a4.x, a4.y, a4.z, a4.w};
    float ww[8] = {w0.x, w0.y, w0.z, w0.w, w1.x, w1.y, w1.z, w1.w};
    #pragma unroll
    for (int i = 0; i < 4; ++i)
      #pragma unroll
      for (int u = 0; u < 8; ++u) accY[i][u] = fmaf(aa[i], ww[u], accY[i][u]);
  }

  float4 bv0 = *(const float4*)(bias + (tc << 2));
  float4 bv1 = *(const float4*)(bias + 64 + (tc << 2));
  float bb[8] = {bv0.x, bv0.y, bv0.z, bv0.w, bv1.x, bv1.y, bv1.z, bv1.w};
  #pragma unroll
  for (int i = 0; i < 4; ++i) {
    size_t row = r0 + (tr << 2) + i;
    float h[8];
    #pragma unroll
    for (int u = 0; u < 8; ++u) h[u] = (accS[i][u] + accY[i][u]) + bb[u];
    *(float4*)(y + row * DD + (tc << 2))      = make_float4(accY[i][0], accY[i][1], accY[i][2], accY[i][3]);
    *(float4*)(y + row * DD + 64 + (tc << 2)) = make_float4(accY[i][4], accY[i][5], accY[i][6], accY[i][7]);
    *(float4*)(hbase + row * DD + (tc << 2))      = make_float4(h[0], h[1], h[2], h[3]);
    *(float4*)(hbase + row * DD + 64 + (tc << 2)) = make_float4(h[4], h[5], h[6], h[7]);
  }
}

// ---------------- Kernel 3: MFMA pairwise dist SCREEN (approx top-8/split) ----
// grid 1024 = 8 batches (XCD-affine) x 32 n-groups(64) x 4 m-splits(512).
// block 256 = 4 waves. Staging via global_load_lds (async, no reg round-trip):
// LDS dest = wave-uniform base + lane*16 by construction. 3 independent MFMA
// accumulator chains (hh, lh, hl) of depth 4. Candidates rescored by k_rsc.
#define GLOAD(MC, BUF) do { \
    _Pragma("unroll") \
    for (int q = 0; q < 4; ++q) { \
      int ks_ = ((q & 1) << 2) + sks; \
      int mrow_ = mbase + ((MC) << 5) + ((q >> 1) << 4) + sr; \
      const u16* src_ = (ks_ < 4 ? xhb : xlb) + ((size_t)mrow_ << 7) + ((ks_ & 3) << 5) + (sg << 3); \
      gload16(src_, (char*)(&Bc[(BUF)][0]) + (((q << 8) + tid) << 4)); \
    } } while (0)

__global__ __launch_bounds__(256, 4) void k_knn(const u16* __restrict__ xh,
                                                const u16* __restrict__ xl,
                                                const float* __restrict__ xx,
                                                ull* __restrict__ cand) {
  __shared__ __align__(16) u16 Bc[2][8192];   // 2 x 16 KB chunk buffers
  __shared__ float xxm[512];

  int tid = threadIdx.x;
  int lane = tid & 63, w = tid >> 6;
  int b = blockIdx.x & 7;                    // XCD-affine batch
  int rest = blockIdx.x >> 3;
  int n0 = (rest & 31) << 6;
  int msplit = rest >> 5;
  int mbase = msplit << 9;
  const u16*  xhb = xh + (((size_t)b << 11) << 7);
  const u16*  xlb = xl + (((size_t)b << 11) << 7);
  const float* xxb = xx + ((size_t)b << 11);

  // staging decode
  int sr = tid & 15;          // row within panel
  int sg = (tid >> 4) & 3;    // k-slot group
  int sks = (tid >> 6) & 3;   // kstep within half

  GLOAD(0, 0);                // async: chunk 0 -> Bc[0]

  { // stage xx for this m-range
    float2 t = *(const float2*)(xxb + mbase + tid * 2);
    xxm[tid * 2] = t.x; xxm[tid * 2 + 1] = t.y;
  }

  int r = lane & 15, g = lane >> 4;
  int myn = n0 + (w << 4) + r;
  float xxn = xxb[myn];

  // A-side (n) frags hoisted: ah = xh rows, al = xl rows
  bf16x8 ah[4], al[4];
  #pragma unroll
  for (int ks = 0; ks < 4; ++ks) {
    ah[ks] = *(const bf16x8*)(xhb + ((size_t)myn << 7) + (ks << 5) + (g << 3));
    al[ks] = *(const bf16x8*)(xlb + ((size_t)myn << 7) + (ks << 5) + (g << 3));
  }

  ull t8[8];
  #pragma unroll
  for (int q = 0; q < 8; ++q) t8[q] = ~0ull;

  __syncthreads();            // vmcnt(0): chunk 0 landed; xxm visible

  int cur = 0;
  for (int mc = 0; mc < 16; ++mc) {
    if (mc < 15) GLOAD(mc + 1, cur ^ 1);     // async into other buffer
    const u16* Bcur = &Bc[cur][0];
    #pragma unroll
    for (int p = 0; p < 2; ++p) {
      f32x4 ahh = {0.f, 0.f, 0.f, 0.f};
      f32x4 alh = {0.f, 0.f, 0.f, 0.f};
      f32x4 ahl = {0.f, 0.f, 0.f, 0.f};
      #pragma unroll
      for (int ks = 0; ks < 4; ++ks) {
        bf16x8 bh = *(const bf16x8*)(Bcur + (((p << 3) + ks) << 9) + (lane << 3));
        bf16x8 bo = *(const bf16x8*)(Bcur + (((p << 3) + 4 + ks) << 9) + (lane << 3));
        ahh = __builtin_amdgcn_mfma_f32_16x16x32_bf16(bh, ah[ks], ahh, 0, 0, 0);
        alh = __builtin_amdgcn_mfma_f32_16x16x32_bf16(bo, ah[ks], alh, 0, 0, 0);
        ahl = __builtin_amdgcn_mfma_f32_16x16x32_bf16(bh, al[ks], ahl, 0, 0, 0);
      }
      float4 xm4 = *(const float4*)(xxm + (mc << 5) + (p << 4) + (g << 2));
      float xmv[4] = {xm4.x, xm4.y, xm4.z, xm4.w};
      int mb0 = mbase + (mc << 5) + (p << 4) + (g << 2);
      #pragma unroll
      for (int e = 0; e < 4; ++e) {
        float dot = (ahh[e] + alh[e]) + ahl[e];
        float d = fmaxf((xxn - 2.f * dot) + xmv[e], 0.f);
        int m = mb0 + e;
        ull cd = (((ull)__float_as_uint(d)) << 32) | (unsigned)m;
        if (m != myn && cd < t8[7]) INS8(t8, cd);
      }
    }
    __syncthreads();          // all waves done reading Bc[cur]; vmcnt(0): next chunk in
    cur ^= 1;
  }

  // merge the 4 g-lanes of each n
  ull* mbuf = (ull*)(&Bc[0][0]);   // 4 waves * 16 n * 4 g * 8 = 16 KB
  #pragma unroll
  for (int q = 0; q < 8; ++q)
    mbuf[(((((w << 4) + r) << 2) + g) << 3) + q] = t8[q];
  __syncthreads();
  if (g == 0) {
    for (int j = 1; j < 4; ++j) {
      #pragma unroll
      for (int q = 0; q < 8; ++q) {
        ull cd = mbuf[(((((w << 4) + r) << 2) + j) << 3) + q];
        if (cd < t8[7]) INS8(t8, cd);
      }
    }
    ull* cp = cand + ((((size_t)b << 11) + myn) << 5) + (msplit << 3);
    #pragma unroll
    for (int q = 0; q < 8; ++q) cp[q] = t8[q];
  }
}

// ---------------- Kernel 3b: EXACT f32 rescore of the 32 candidates/row ----
__global__ __launch_bounds__(256) void k_rsc(const float* __restrict__ x,
                                             const float* __restrict__ xx,
                                             const ull* __restrict__ cand,
                                             int* __restrict__ nbr) {
  __shared__ ull ex[256];
  int tid = threadIdx.x;
  int rloc = tid >> 5;               // 8 rows per block
  int c = tid & 31;
  int row = blockIdx.x * 8 + rloc;
  int b = row >> 11;
  ull cd = cand[((size_t)row << 5) + c];
  int m = (int)(cd & 0xffffffffu);
  const float* xn = x + (size_t)row * DD;
  const float* xm = x + ((size_t)(b << 11) + m) * DD;
  float acc = 0.f;
  #pragma unroll
  for (int d4 = 0; d4 < 32; ++d4) {
    float4 a = *(const float4*)(xn + (d4 << 2));
    float4 v = *(const float4*)(xm + (d4 << 2));
    acc = fmaf(a.x, v.x, acc);
    acc = fmaf(a.y, v.y, acc);
    acc = fmaf(a.z, v.z, acc);
    acc = fmaf(a.w, v.w, acc);
  }
  float dist = fmaxf((xx[row] - 2.f * acc) + xx[(b << 11) + m], 0.f);
  ex[tid] = (((ull)__float_as_uint(dist)) << 32) | (unsigned)m;
  __syncthreads();
  if (c == 0) {
    ull t8[8];
    #pragma unroll
    for (int q = 0; q < 8; ++q) t8[q] = ~0ull;
    #pragma unroll
    for (int q = 0; q < 32; ++q) {
      ull v = ex[(rloc << 5) + q];
      if (v < t8[7]) INS8(t8, v);
    }
    int* op = nbr + (size_t)row * 8;
    #pragma unroll
    for (int q = 0; q < 8; ++q) op[q] = (int)(t8[q] & 0xffffffffu);
  }
}

// ---------------- Kernel 4: gather + KAN rational + BN partial sums ----------------
__global__ __launch_bounds__(256) void k_kan(const float* __restrict__ hbase,
                                             const float* __restrict__ y,
                                             const int* __restrict__ nbr,
                                             const float* __restrict__ kan_a,
                                             const float* __restrict__ kan_b,
                                             float* __restrict__ hkan,
                                             double* __restrict__ sums) {
  __shared__ double redA[256], redB[256];
  int f = threadIdx.x & 127;
  int half = threadIdx.x >> 7;
  int r0 = blockIdx.x * 64 + half * 32;
  int bb = r0 >> 11;
  const float* yb = y + ((size_t)bb << 11) * DD;
  float a0 = kan_a[f * 3 + 0], a1 = kan_a[f * 3 + 1], a2 = kan_a[f * 3 + 2];
  float b0 = kan_b[f * 2 + 0], b1 = kan_b[f * 2 + 1];
  float disf = (float)(1.0 / sqrt((double)(8.0f + 1e-6f)));
  float cf = disf * disf;
  double sh = 0.0, sh2 = 0.0;
  for (int i = 0; i < 32; ++i) {
    int r = r0 + i;
    const int* np_ = nbr + (size_t)r * 8;
    float t = 0.f;
    #pragma unroll
    for (int j = 0; j < 8; ++j) {
      int m = np_[j];
      float yv = yb[(size_t)m * DD + f];
      t = fmaf(cf, yv, t);
    }
    float h = hbase[(size_t)r * DD + f] + t;
    float h2 = h * h;
    float num = (a0 + a1 * h) + a2 * h2;
    float den = 1.0f + fabsf(b0 * h + b1 * h2);
    float hk = num / (den + 1e-8f);
    hkan[(size_t)r * DD + f] = hk;
    sh += (double)hk; sh2 += (double)hk * (double)hk;
  }
  redA[threadIdx.x] = sh; redB[threadIdx.x] = sh2;
  __syncthreads();
  if (half == 0) {
    atomicAdd(&sums[f], sh + redA[f + 128]);
    atomicAdd(&sums[128 + f], sh2 + redB[f + 128]);
  }
}

// ---------------- Kernel 5: BN finalize + normalize ----------------
__global__ __launch_bounds__(256) void k_bn(const float* __restrict__ hkan,
                                            const double* __restrict__ sums,
                                            const float* __restrict__ gamma,
                                            const float* __restrict__ beta,
                                            float* __restrict__ out) {
  __shared__ float mn[128], sc[128], bt[128];
  int tid = threadIdx.x;
  if (tid < 128) {
    double M = (double)(BB * NN);
    double mean = sums[tid] / M;
    double var = sums[128 + tid] / M - mean * mean;
    if (var < 0.0) var = 0.0;
    mn[tid] = (float)mean;
    sc[tid] = (float)(1.0 / sqrt(var + 1e-5)) * gamma[tid];
    bt[tid] = beta[tid];
  }
  __syncthreads();
  const int total4 = BB * NN * DD / 4;
  for (int i4 = blockIdx.x * blockDim.x + threadIdx.x; i4 < total4;
       i4 += gridDim.x * blockDim.x) {
    float4 v = ((const float4*)hkan)[i4];
    int fb = (i4 * 4) & 127;
    float4 o;
    o.x = (v.x - mn[fb + 0]) * sc[fb + 0] + bt[fb + 0];
    o.y = (v.y - mn[fb + 1]) * sc[fb + 1] + bt[fb + 1];
    o.z = (v.z - mn[fb + 2]) * sc[fb + 2] + bt[fb + 2];
    o.w = (v.w - mn[fb + 3]) * sc[fb + 3] + bt[fb + 3];
    ((float4*)out)[i4] = o;
  }
}

extern "C" void kernel_launch(void* const* d_in, const int* in_sizes, int n_in,
                              void* d_out, int out_size, void* d_ws, size_t ws_size,
                              hipStream_t stream) {
  const float* x     = (const float*)d_in[0];
  const float* Ws    = (const float*)d_in[1];
  const float* Wn    = (const float*)d_in[2];
  const float* ka    = (const float*)d_in[3];
  const float* kb    = (const float*)d_in[4];
  const float* bias  = (const float*)d_in[5];
  const float* gamma = (const float*)d_in[6];
  const float* beta  = (const float*)d_in[7];
  float* out = (float*)d_out;

  char* ws = (char*)d_ws;
  float*  xx    = (float*)(ws + 0);          //  64 KB
  int*    nbr   = (int*)(ws + 65536);        // 512 KB
  double* sums  = (double*)(ws + 589824);    //   2 KB
  float*  y     = (float*)(ws + 1048576);    //   8 MB
  float*  hbase = (float*)(ws + 9437184);    //   8 MB
  float*  hkan  = (float*)(ws + 17825792);   //   8 MB (aliased below until k_kan)
  ull*    cand  = (ull*)(ws + 17825792);     //   4 MB (dead before k_kan writes hkan)
  u16*    xh    = (u16*)(ws + 22020096);     //   4 MB (dead before k_kan writes hkan)
  u16*    xl    = (u16*)d_out;               //   4 MB scratch in d_out; k_bn overwrites all of d_out last

  hipMemsetAsync(sums, 0, 256 * sizeof(double), stream);
  k_cvx <<<4096, 256, 0, stream>>>(x, xx, xh, xl);
  k_gemm<<<256,  256, 0, stream>>>(x, Ws, Wn, bias, hbase, y);
  k_knn <<<1024, 256, 0, stream>>>(xh, xl, xx, cand);
  k_rsc <<<2048, 256, 0, stream>>>(x, xx, cand, nbr);
  k_kan <<<256,  256, 0, stream>>>(hbase, y, nbr, ka, kb, hkan, sums);
  k_bn  <<<1024, 256, 0, stream>>>(hkan, sums, gamma, beta, out);
}